// Round 3
// baseline (501.423 us; speedup 1.0000x reference)
//
#include <hip/hip_runtime.h>
#include <math.h>

#define NQ 9
#define KK 3
#define S 16
#define H 128
#define BB 16
#define D 512

// ---------------------------------------------------------------------------
// Kernel 1: sequential LSTM + snapshot recurrence in double precision.
// CRITICAL reference semantics: _take_snapshots never mutates the caller's
// psi, so EVERY timestep starts the collapse from the ORIGINAL raw psi.
// We keep a pristine copy (p0r/p0i) and reset the working psi each t.
// One block per batch, 512 threads (one per amplitude).
// Emits per-(b,t,q) Hermitian 2x2 matrices {m00, re01, im01, m11} (fp32) to
// ws, and last_bv (amps at t=15) to the output tail.
// ---------------------------------------------------------------------------
__global__ __launch_bounds__(512)
void seq_kernel(const float* __restrict__ snapshot,
                const float* __restrict__ bcv,
                const float* __restrict__ rho,
                const float* __restrict__ h0,
                const float* __restrict__ c0,
                const float* __restrict__ W_ih,
                const float* __restrict__ W_hh,
                const float* __restrict__ b_ih,
                const float* __restrict__ b_hh,
                const float* __restrict__ Wp,
                const float* __restrict__ bp,
                float4* __restrict__ mats,      // [BB][S][NQ]
                float* __restrict__ last_bv)    // d_out + BB*2*D*D
{
  const int b   = blockIdx.x;
  const int tid = threadIdx.x;

  __shared__ double p0r[D], p0i[D];          // pristine psi (never modified)
  __shared__ double psi_re[D], psi_im[D];    // working psi (reset each t)
  __shared__ double hbuf[H], cbuf[H];
  __shared__ double xbuf[NQ + NQ*KK];        // [snap(9), amps(27)]
  __shared__ double gbuf[512];
  __shared__ double redp[8], redm[8];
  __shared__ double bc_rs;

  // init state
  p0r[tid] = (double)rho[b*1024 + tid];
  p0i[tid] = (double)rho[b*1024 + 512 + tid];
  if (tid < H)      { hbuf[tid] = (double)h0[b*H + tid]; cbuf[tid] = (double)c0[b*H + tid]; }
  if (tid < NQ)     xbuf[tid]      = (double)snapshot[b*NQ + tid];
  if (tid < NQ*KK)  xbuf[NQ + tid] = (double)bcv[b*NQ*KK + tid];
  __syncthreads();

  // emit mats for t = 0 (raw snapshot + basis_comp_vector)
  if (tid < NQ) {
    double s  = xbuf[tid];
    double v0 = xbuf[NQ + tid*3];
    double v1 = xbuf[NQ + tid*3 + 1];
    double v2 = xbuf[NQ + tid*3 + 2];
    mats[(b*S + 0)*NQ + tid] = make_float4(
        (float)(0.5*(1.0 + 3.0*s*v2)), (float)(1.5*s*v0),
        (float)(-1.5*s*v1),            (float)(0.5*(1.0 - 3.0*s*v2)));
  }

  for (int t = 1; t < S; ++t) {
    // ---- LSTM gates: g[tid] = x@W_ih^T + h@W_hh^T + b_ih + b_hh
    double g = (double)b_ih[tid] + (double)b_hh[tid];
    {
      const float4* wi = (const float4*)(W_ih + tid*36);
      #pragma unroll
      for (int k4 = 0; k4 < 9; ++k4) {
        float4 w = wi[k4];
        g += (double)w.x*xbuf[k4*4]   + (double)w.y*xbuf[k4*4+1]
           + (double)w.z*xbuf[k4*4+2] + (double)w.w*xbuf[k4*4+3];
      }
      const float4* wh = (const float4*)(W_hh + tid*H);
      for (int k4 = 0; k4 < 32; ++k4) {
        float4 w = wh[k4];
        g += (double)w.x*hbuf[k4*4]   + (double)w.y*hbuf[k4*4+1]
           + (double)w.z*hbuf[k4*4+2] + (double)w.w*hbuf[k4*4+3];
      }
    }
    gbuf[tid] = g;
    __syncthreads();

    // ---- cell update (i,f,g,o per jnp.split)
    if (tid < H) {
      double ig = 1.0/(1.0 + exp(-gbuf[tid]));
      double fg = 1.0/(1.0 + exp(-gbuf[H + tid]));
      double gg = tanh(gbuf[2*H + tid]);
      double og = 1.0/(1.0 + exp(-gbuf[3*H + tid]));
      double c  = fg*cbuf[tid] + ig*gg;
      cbuf[tid] = c;
      hbuf[tid] = og*tanh(c);
    }
    __syncthreads();

    // ---- logits[n,k] = h @ Wp[n,k,:] + bp[n,k]
    if (tid < NQ*KK) {
      double acc = (double)bp[tid];
      const float4* wp = (const float4*)(Wp + tid*H);
      for (int k4 = 0; k4 < 32; ++k4) {
        float4 w = wp[k4];
        acc += (double)w.x*hbuf[k4*4]   + (double)w.y*hbuf[k4*4+1]
             + (double)w.z*hbuf[k4*4+2] + (double)w.w*hbuf[k4*4+3];
      }
      gbuf[tid] = acc;
    }
    __syncthreads();

    // ---- softmax over k then sqrt -> amps
    if (tid < NQ) {
      double l0 = gbuf[tid*3], l1 = gbuf[tid*3+1], l2 = gbuf[tid*3+2];
      double m  = fmax(l0, fmax(l1, l2));
      double e0 = exp(l0 - m), e1 = exp(l1 - m), e2 = exp(l2 - m);
      double inv = 1.0/(e0 + e1 + e2);
      xbuf[NQ + tid*3 + 0] = sqrt(e0*inv);
      xbuf[NQ + tid*3 + 1] = sqrt(e1*inv);
      xbuf[NQ + tid*3 + 2] = sqrt(e2*inv);
    }

    // ---- reset working psi to the PRISTINE state (reference semantics:
    //      take_snapshots gets the original psi every timestep)
    psi_re[tid] = p0r[tid];
    psi_im[tid] = p0i[tid];
    __syncthreads();

    // ---- take_snapshots: collapse qubits 0..8; one thread per amplitude
    for (int q = 0; q < NQ; ++q) {
      double a1 = xbuf[NQ + q*3], a2 = xbuf[NQ + q*3 + 1], a3 = xbuf[NQ + q*3 + 2];
      double an = sqrt(a1*a1 + a2*a2 + a3*a3);
      double t3 = a3 + an;
      double n2 = 1.0/(2.0*an*t3);        // nrm^2
      double Pp00 = n2*t3*t3;
      double Pp11 = n2*(a1*a1 + a2*a2);
      double Pr   = n2*t3*a1;             // Re(Pp01)
      double Pi   = -n2*t3*a2;            // Im(Pp01); Pm00=Pp11 Pm11=Pp00 Pm01=-Pp01

      const int sh   = 8 - q;             // qubit q owns bit (8-q)
      const int bit  = (tid >> sh) & 1;
      const int part = tid ^ (1 << sh);
      double sr = psi_re[tid],  si = psi_im[tid];
      double qr = psi_re[part], qi = psi_im[part];

      double nr, ni, mr, mi;
      if (bit == 0) {
        nr = Pp00*sr + Pr*qr - Pi*qi;
        ni = Pp00*si + Pr*qi + Pi*qr;
        mr = Pp11*sr - (Pr*qr - Pi*qi);
        mi = Pp11*si - (Pr*qi + Pi*qr);
      } else {
        nr = Pr*qr + Pi*qi + Pp11*sr;
        ni = Pr*qi - Pi*qr + Pp11*si;
        mr = -(Pr*qr + Pi*qi) + Pp00*sr;
        mi = -(Pr*qi - Pi*qr) + Pp00*si;
      }

      double lp = nr*nr + ni*ni;
      double lm = mr*mr + mi*mi;
      // wave-level shuffle reduction (64 lanes), then combine 8 wave partials
      #pragma unroll
      for (int off = 32; off > 0; off >>= 1) {
        lp += __shfl_down(lp, off, 64);
        lm += __shfl_down(lm, off, 64);
      }
      const int wid = tid >> 6, lane = tid & 63;
      if (lane == 0) { redp[wid] = lp; redm[wid] = lm; }
      __syncthreads();
      if (tid == 0) {
        double pp = 0.0, pm = 0.0;
        #pragma unroll
        for (int w = 0; w < 8; ++w) { pp += redp[w]; pm += redm[w]; }
        bc_rs = 1.0/sqrt(pp);
        xbuf[q] = pp - pm;                // snapshot value s_q
      }
      __syncthreads();
      double rs = bc_rs;
      psi_re[tid] = nr*rs;                // collapse onto normalized plus branch
      psi_im[tid] = ni*rs;
      __syncthreads();
    }

    // ---- emit mats for this t
    if (tid < NQ) {
      double s  = xbuf[tid];
      double v0 = xbuf[NQ + tid*3];
      double v1 = xbuf[NQ + tid*3 + 1];
      double v2 = xbuf[NQ + tid*3 + 2];
      mats[(b*S + t)*NQ + tid] = make_float4(
          (float)(0.5*(1.0 + 3.0*s*v2)), (float)(1.5*s*v0),
          (float)(-1.5*s*v1),            (float)(0.5*(1.0 - 3.0*s*v2)));
    }
  }

  if (tid < NQ*KK) last_bv[b*NQ*KK + tid] = (float)xbuf[NQ + tid];
}

// ---------------------------------------------------------------------------
// Kernel 2: out[b] = (1/S) * sum_t kron(M0..M8), factored as
// Top(q0..q3, 16x16) (x) Bot(q4..q8, 32x32):
//   out[row,col] = sum_t Top_t[row>>5, col>>5] * Bot_t[row&31, col&31]
// One block per (b,row); 512 threads = 512 cols; coalesced row writes.
// ---------------------------------------------------------------------------
__device__ __forceinline__ void herm_entry(float4 m, int rb, int cb, float& er, float& ei) {
  if (rb == 0) { if (cb == 0) { er = m.x; ei = 0.f; } else { er = m.y; ei = m.z; } }
  else         { if (cb == 0) { er = m.y; ei = -m.z; } else { er = m.w; ei = 0.f; } }
}

__global__ __launch_bounds__(512)
void kron_kernel(const float4* __restrict__ mats_g, float* __restrict__ out)
{
  const int b   = blockIdx.y;
  const int row = blockIdx.x;
  const int tid = threadIdx.x;
  const int rT  = row >> 5;
  const int rB  = row & 31;

  __shared__ float4 mats[S*NQ];      // 144
  __shared__ float2 topRow[S*16];    // Top_t[rT, cT]
  __shared__ float2 botRow[S*32];    // Bot_t[rB, cB]

  if (tid < S*NQ) mats[tid] = mats_g[b*S*NQ + tid];
  __syncthreads();

  if (tid < 256) {                   // t = tid>>4, cT = tid&15
    int t = tid >> 4, cT = tid & 15;
    float re = 1.f, im = 0.f;
    #pragma unroll
    for (int q = 0; q < 4; ++q) {
      int rb = (rT >> (3 - q)) & 1;
      int cb = (cT >> (3 - q)) & 1;
      float er, ei;
      herm_entry(mats[t*NQ + q], rb, cb, er, ei);
      float nr = re*er - im*ei;
      im = re*ei + im*er;
      re = nr;
    }
    topRow[tid] = make_float2(re, im);
  }
  {                                  // t = tid>>5, cB = tid&31
    int t = tid >> 5, cB = tid & 31;
    float re = 1.f, im = 0.f;
    #pragma unroll
    for (int q = 0; q < 5; ++q) {
      int rb = (rB >> (4 - q)) & 1;
      int cb = (cB >> (4 - q)) & 1;
      float er, ei;
      herm_entry(mats[t*NQ + 4 + q], rb, cb, er, ei);
      float nr = re*er - im*ei;
      im = re*ei + im*er;
      re = nr;
    }
    botRow[tid] = make_float2(re, im);
  }
  __syncthreads();

  const int cT = tid >> 5, cB = tid & 31;
  float accr = 0.f, acci = 0.f;
  #pragma unroll
  for (int t = 0; t < S; ++t) {
    float2 a  = topRow[t*16 + cT];
    float2 bo = botRow[t*32 + cB];
    accr += a.x*bo.x - a.y*bo.y;
    acci += a.x*bo.y + a.y*bo.x;
  }
  const float invS = 1.f/(float)S;
  size_t base = ((size_t)b*2)*(D*D) + (size_t)row*D + tid;
  out[base]               = accr*invS;   // real plane
  out[base + (size_t)D*D] = acci*invS;   // imag plane
}

extern "C" void kernel_launch(void* const* d_in, const int* in_sizes, int n_in,
                              void* d_out, int out_size, void* d_ws, size_t ws_size,
                              hipStream_t stream) {
  const float* snapshot = (const float*)d_in[0];
  const float* bcv      = (const float*)d_in[1];
  const float* rho      = (const float*)d_in[2];
  const float* h0       = (const float*)d_in[3];
  const float* c0       = (const float*)d_in[4];
  const float* W_ih     = (const float*)d_in[5];
  const float* W_hh     = (const float*)d_in[6];
  const float* b_ih     = (const float*)d_in[7];
  const float* b_hh     = (const float*)d_in[8];
  const float* Wp       = (const float*)d_in[9];
  const float* bp       = (const float*)d_in[10];

  float*  out     = (float*)d_out;
  float4* mats    = (float4*)d_ws;                 // 16*16*9 float4 = 36 KB
  float*  last_bv = out + (size_t)BB*2*D*D;        // output chunk 1

  seq_kernel<<<BB, 512, 0, stream>>>(snapshot, bcv, rho, h0, c0,
                                     W_ih, W_hh, b_ih, b_hh, Wp, bp,
                                     mats, last_bv);

  dim3 grid(D, BB);
  kron_kernel<<<grid, 512, 0, stream>>>(mats, out);
}

// Round 4
// 225.941 us; speedup vs baseline: 2.2193x; 2.2193x over previous
//
#include <hip/hip_runtime.h>
#include <math.h>

#define NQ 9
#define KK 3
#define S 16
#define H 128
#define BB 16
#define D 512
#define DD (D*D)

__device__ __forceinline__ float sigf(float x){ return 1.f/(1.f + __expf(-x)); }

// ---------------------------------------------------------------------------
// Kernel 1: sequential LSTM + snapshot recurrence, fp32, one block per batch
// (512 thr = 8 waves). Weights register-resident. Collapse = rank-1 halving
// contraction on wave 0 only (shuffles, no barriers), prob_m = |phi|^2-prob_p.
// Reference semantics: each timestep's collapse starts from the PRISTINE psi.
// ---------------------------------------------------------------------------
__global__ __launch_bounds__(512, 2)
void seq_kernel(const float* __restrict__ snapshot,
                const float* __restrict__ bcv,
                const float* __restrict__ rho,
                const float* __restrict__ h0,
                const float* __restrict__ c0,
                const float* __restrict__ W_ih,
                const float* __restrict__ W_hh,
                const float* __restrict__ b_ih,
                const float* __restrict__ b_hh,
                const float* __restrict__ Wp,
                const float* __restrict__ bp,
                float4* __restrict__ mats,      // [BB][S][NQ]
                float* __restrict__ last_bv)
{
  const int b    = blockIdx.x;
  const int tid  = threadIdx.x;
  const int lane = tid & 63;
  const int w    = tid >> 6;

  __shared__ __align__(16) float xh[164];     // x(36) then h(128)
  __shared__ float gbuf[512];
  __shared__ float cbuf[128];
  __shared__ float prj[27];
  __shared__ __align__(16) float psi0[1024];  // pristine psi: re[512], im[512]

  // ---- preload weights into registers (reused for all 15 steps)
  float4 wih[9], whh[32];
  {
    const float4* wi = (const float4*)(W_ih + tid*36);
    #pragma unroll
    for (int k = 0; k < 9; ++k) wih[k] = wi[k];
    const float4* wh = (const float4*)(W_hh + tid*H);
    #pragma unroll
    for (int k = 0; k < 32; ++k) whh[k] = wh[k];
  }
  const float bias = b_ih[tid] + b_hh[tid];
  float2 wpv[4]; float bpv[4];
  #pragma unroll
  for (int i = 0; i < 4; ++i) {
    int u = w + 8*i;
    if (u < 27) { wpv[i] = *(const float2*)(Wp + u*H + 2*lane); bpv[i] = bp[u]; }
    else        { wpv[i] = make_float2(0.f, 0.f); bpv[i] = 0.f; }
  }

  // ---- init state
  psi0[tid]       = rho[b*1024 + tid];
  psi0[512 + tid] = rho[b*1024 + 512 + tid];
  if (tid < 128) { cbuf[tid] = c0[b*H + tid]; xh[36 + tid] = h0[b*H + tid]; }
  if (tid < NQ)  xh[tid]      = snapshot[b*NQ + tid];
  if (tid < 27)  xh[NQ + tid] = bcv[b*27 + tid];
  __syncthreads();

  // t=0 mats from raw inputs
  if (tid < NQ) {
    float s = xh[tid], v0 = xh[9+tid*3], v1 = xh[9+tid*3+1], v2 = xh[9+tid*3+2];
    mats[(b*S + 0)*NQ + tid] = make_float4(
        0.5f*(1.f + 3.f*s*v2), 1.5f*s*v0, -1.5f*s*v1, 0.5f*(1.f - 3.f*s*v2));
  }

  // wave0: |psi0|^2 (needed for q=0's prob_m each step)
  float norm0 = 0.f;
  if (w == 0) {
    const float4* p4 = (const float4*)psi0;
    float4 r0 = p4[lane*2], r1 = p4[lane*2+1];
    float4 i0 = p4[128 + lane*2], i1 = p4[128 + lane*2+1];
    float ls = r0.x*r0.x + r0.y*r0.y + r0.z*r0.z + r0.w*r0.w
             + r1.x*r1.x + r1.y*r1.y + r1.z*r1.z + r1.w*r1.w
             + i0.x*i0.x + i0.y*i0.y + i0.z*i0.z + i0.w*i0.w
             + i1.x*i1.x + i1.y*i1.y + i1.z*i1.z + i1.w*i1.w;
    #pragma unroll
    for (int m = 32; m > 0; m >>= 1) ls += __shfl_xor(ls, m, 64);
    norm0 = ls;
  }

  for (int t = 1; t < S; ++t) {
    // ---- gates (all 512 threads, register weights, broadcast LDS reads)
    {
      const float4* x4 = (const float4*)xh;
      float g0 = bias, g1 = 0.f, g2 = 0.f, g3 = 0.f;
      #pragma unroll
      for (int k = 0; k < 9; ++k) {
        float4 wv = wih[k], xv = x4[k];
        g0 += wv.x*xv.x; g1 += wv.y*xv.y; g2 += wv.z*xv.z; g3 += wv.w*xv.w;
      }
      #pragma unroll
      for (int k = 0; k < 32; ++k) {
        float4 wv = whh[k], xv = x4[9 + k];
        g0 += wv.x*xv.x; g1 += wv.y*xv.y; g2 += wv.z*xv.z; g3 += wv.w*xv.w;
      }
      gbuf[tid] = (g0 + g1) + (g2 + g3);
    }
    __syncthreads();                                        // B1

    // ---- cell update (i,f,g,o per jnp.split)
    if (tid < 128) {
      float ig = sigf(gbuf[tid]);
      float fg = sigf(gbuf[128 + tid]);
      float gg = tanhf(gbuf[256 + tid]);
      float og = sigf(gbuf[384 + tid]);
      float c  = fg*cbuf[tid] + ig*gg;
      cbuf[tid] = c;
      xh[36 + tid] = og*tanhf(c);
    }
    __syncthreads();                                        // B2

    // ---- projection logits: unit u = w + 8i, wave-level butterfly reduce
    {
      float2 hv = *(const float2*)(xh + 36 + 2*lane);
      #pragma unroll
      for (int i = 0; i < 4; ++i) {
        float p = wpv[i].x*hv.x + wpv[i].y*hv.y;
        #pragma unroll
        for (int m = 32; m > 0; m >>= 1) p += __shfl_xor(p, m, 64);
        int u = w + 8*i;
        if (u < 27 && lane == 0) prj[u] = p + bpv[i];
      }
    }
    __syncthreads();                                        // B3

    // ---- wave 0: softmax -> amps, halving-contraction collapse, emit
    if (w == 0) {
      float a1 = 0.f, a2 = 0.f, a3 = 0.f;
      if (lane < NQ) {
        float l0 = prj[lane*3], l1 = prj[lane*3+1], l2 = prj[lane*3+2];
        float mx = fmaxf(l0, fmaxf(l1, l2));
        float e0 = __expf(l0 - mx), e1 = __expf(l1 - mx), e2 = __expf(l2 - mx);
        float inv = 1.f/(e0 + e1 + e2);
        a1 = sqrtf(e0*inv); a2 = sqrtf(e1*inv); a3 = sqrtf(e2*inv);
      }
      // working phi <- pristine psi (8 complex per lane)
      float wr[8], wim[8];
      {
        const float4* p4 = (const float4*)psi0;
        float4 r0 = p4[lane*2], r1 = p4[lane*2+1];
        float4 i0 = p4[128 + lane*2], i1 = p4[128 + lane*2+1];
        wr[0]=r0.x; wr[1]=r0.y; wr[2]=r0.z; wr[3]=r0.w;
        wr[4]=r1.x; wr[5]=r1.y; wr[6]=r1.z; wr[7]=r1.w;
        wim[0]=i0.x; wim[1]=i0.y; wim[2]=i0.z; wim[3]=i0.w;
        wim[4]=i1.x; wim[5]=i1.y; wim[6]=i1.z; wim[7]=i1.w;
      }
      float sqv  = 0.f;
      float nphi = norm0;
      #pragma unroll
      for (int q = 0; q < NQ; ++q) {
        float b1 = __shfl(a1, q, 64), b2 = __shfl(a2, q, 64), b3 = __shfl(a3, q, 64);
        float an = sqrtf(b1*b1 + b2*b2 + b3*b3);
        float t3 = b3 + an;
        float n1 = 1.f/sqrtf(2.f*an*t3);
        float k0 = n1*t3, k1r = n1*b1, k1i = -n1*b2;   // conj(p+) components
        const int R = 512 >> q;
        float lp = 0.f;
        if (R >= 16) {
          const int half = R >> 4;                     // partner lane offset
          const bool act = lane < half;
          float cr[8], ci[8];
          #pragma unroll
          for (int j = 0; j < 8; ++j) {
            float pr = __shfl(wr[j],  lane + half, 64);
            float pi = __shfl(wim[j], lane + half, 64);
            cr[j] = k0*wr[j]  + k1r*pr - k1i*pi;
            ci[j] = k0*wim[j] + k1r*pi + k1i*pr;
          }
          if (act) {
            #pragma unroll
            for (int j = 0; j < 8; ++j) lp += cr[j]*cr[j] + ci[j]*ci[j];
          }
          #pragma unroll
          for (int j = 0; j < 8; ++j) { wr[j] = cr[j]; wim[j] = ci[j]; }
        } else {
          const int hw = R >> 1;                       // 4, 2, 1 (lane 0 only)
          float cr[4], ci[4];
          #pragma unroll
          for (int j = 0; j < 4; ++j) {
            if (j < hw) {
              cr[j] = k0*wr[j]  + k1r*wr[j+hw] - k1i*wim[j+hw];
              ci[j] = k0*wim[j] + k1r*wim[j+hw] + k1i*wr[j+hw];
            }
          }
          if (lane == 0) {
            #pragma unroll
            for (int j = 0; j < 4; ++j) if (j < hw) lp += cr[j]*cr[j] + ci[j]*ci[j];
          }
          #pragma unroll
          for (int j = 0; j < 4; ++j) if (j < hw) { wr[j] = cr[j]; wim[j] = ci[j]; }
        }
        #pragma unroll
        for (int m = 32; m > 0; m >>= 1) lp += __shfl_xor(lp, m, 64);
        if (lane == q) sqv = 2.f*lp - nphi;            // s_q = pp - (|phi|^2 - pp)
        float rs = 1.f/sqrtf(lp);
        #pragma unroll
        for (int j = 0; j < 8; ++j) { wr[j] *= rs; wim[j] *= rs; }
        nphi = 1.f;                                    // normalized from q>=1
      }
      // emit: new x = [snap, amps] and mats row for this t
      if (lane < NQ) {
        xh[lane] = sqv;
        xh[9 + lane*3]     = a1;
        xh[9 + lane*3 + 1] = a2;
        xh[9 + lane*3 + 2] = a3;
        mats[(b*S + t)*NQ + lane] = make_float4(
            0.5f*(1.f + 3.f*sqv*a3), 1.5f*sqv*a1,
            -1.5f*sqv*a2,            0.5f*(1.f - 3.f*sqv*a3));
      }
    }
    __syncthreads();                                        // B4
  }

  if (tid < 27) last_bv[b*27 + tid] = xh[9 + tid];
}

// ---------------------------------------------------------------------------
// Kernel 2: out[b] = (1/S) sum_t Top(q0..3) (x) Bot(q4..8).
// 8 rows per block: grid (64, 16). botRows staged in LDS (32 KB), topRow
// hoisted into registers. Coalesced row writes.
// ---------------------------------------------------------------------------
__device__ __forceinline__ void herm_entry(float4 m, int rb, int cb, float& er, float& ei) {
  if (rb == 0) { if (cb == 0) { er = m.x; ei = 0.f; } else { er = m.y; ei = m.z; } }
  else         { if (cb == 0) { er = m.y; ei = -m.z; } else { er = m.w; ei = 0.f; } }
}

__global__ __launch_bounds__(512)
void kron_kernel(const float4* __restrict__ mats_g, float* __restrict__ out)
{
  const int b   = blockIdx.y;
  const int bm  = blockIdx.x;          // 0..63: rows [8bm, 8bm+8)
  const int tid = threadIdx.x;
  const int rT  = bm >> 2;
  const int rB0 = (bm & 3) << 3;

  __shared__ float4 mats[S*NQ];
  __shared__ float2 top[S*16];         // [t][cT] for this rT
  __shared__ float2 bot[8][S*32];      // [r][t][cB]

  if (tid < S*NQ) mats[tid] = mats_g[b*S*NQ + tid];
  __syncthreads();

  if (tid < 256) {                     // t = tid>>4, cT = tid&15
    int t = tid >> 4, cT = tid & 15;
    float re = 1.f, im = 0.f;
    #pragma unroll
    for (int q = 0; q < 4; ++q) {
      int rb = (rT >> (3 - q)) & 1, cb = (cT >> (3 - q)) & 1;
      float er, ei; herm_entry(mats[t*NQ + q], rb, cb, er, ei);
      float nr = re*er - im*ei; im = re*ei + im*er; re = nr;
    }
    top[tid] = make_float2(re, im);
  }
  {
    const int r_  = tid >> 6;
    const int t_  = (tid >> 2) & 15;
    const int cB0 = (tid & 3) << 3;
    const int rB  = rB0 + r_;
    #pragma unroll
    for (int i = 0; i < 8; ++i) {
      int cB = cB0 + i;
      float re = 1.f, im = 0.f;
      #pragma unroll
      for (int q = 0; q < 5; ++q) {
        int rb = (rB >> (4 - q)) & 1, cb = (cB >> (4 - q)) & 1;
        float er, ei; herm_entry(mats[t_*NQ + 4 + q], rb, cb, er, ei);
        float nr = re*er - im*ei; im = re*ei + im*er; re = nr;
      }
      bot[r_][t_*32 + cB] = make_float2(re, im);
    }
  }
  __syncthreads();

  const int cT = tid >> 5, cB = tid & 31;
  float2 tr[16];
  #pragma unroll
  for (int t = 0; t < 16; ++t) tr[t] = top[t*16 + cT];
  const float invS = 1.f/16.f;
  #pragma unroll
  for (int r = 0; r < 8; ++r) {
    float ar = 0.f, ai = 0.f;
    #pragma unroll
    for (int t = 0; t < 16; ++t) {
      float2 a = tr[t], bo = bot[r][t*32 + cB];
      ar += a.x*bo.x - a.y*bo.y;
      ai += a.x*bo.y + a.y*bo.x;
    }
    int row = (bm << 3) + r;
    size_t base = ((size_t)b*2)*DD + (size_t)row*D + tid;
    out[base]      = ar*invS;
    out[base + DD] = ai*invS;
  }
}

extern "C" void kernel_launch(void* const* d_in, const int* in_sizes, int n_in,
                              void* d_out, int out_size, void* d_ws, size_t ws_size,
                              hipStream_t stream) {
  const float* snapshot = (const float*)d_in[0];
  const float* bcv      = (const float*)d_in[1];
  const float* rho      = (const float*)d_in[2];
  const float* h0       = (const float*)d_in[3];
  const float* c0       = (const float*)d_in[4];
  const float* W_ih     = (const float*)d_in[5];
  const float* W_hh     = (const float*)d_in[6];
  const float* b_ih     = (const float*)d_in[7];
  const float* b_hh     = (const float*)d_in[8];
  const float* Wp       = (const float*)d_in[9];
  const float* bp       = (const float*)d_in[10];

  float*  out     = (float*)d_out;
  float4* mats    = (float4*)d_ws;                 // 16*16*9 float4 = 36 KB
  float*  last_bv = out + (size_t)BB*2*DD;         // output chunk 1

  seq_kernel<<<BB, 512, 0, stream>>>(snapshot, bcv, rho, h0, c0,
                                     W_ih, W_hh, b_ih, b_hh, Wp, bp,
                                     mats, last_bv);

  dim3 grid(64, BB);
  kron_kernel<<<grid, 512, 0, stream>>>(mats, out);
}

// Round 5
// 225.224 us; speedup vs baseline: 2.2263x; 1.0032x over previous
//
#include <hip/hip_runtime.h>
#include <math.h>

#define NQ 9
#define KK 3
#define S 16
#define H 128
#define BB 16
#define D 512
#define DD (D*D)

__device__ __forceinline__ float sigf(float x){ return 1.f/(1.f + __expf(-x)); }

// ---------------------------------------------------------------------------
// Kernel 1: sequential LSTM + snapshot recurrence, fp32, one block/batch
// (512 thr = 8 waves). Weights register-resident. 3 barriers/step.
// Collapse: deferred-normalization halving contraction; state layout
// flat = j*64 + lane (qubits 0-2 = register bits j2..j0, qubits 3-8 = lane
// bits 5..0) so q0-q2 contract without shuffles and q3-q8 shuffle ONE value.
// s_q = 2*L_q/L_{q-1} - 1 (projector completeness), L_q = |phi_q|^2.
// Reference semantics: every timestep's collapse starts from pristine psi0.
// ---------------------------------------------------------------------------
__global__ __launch_bounds__(512, 2)
void seq_kernel(const float* __restrict__ snapshot,
                const float* __restrict__ bcv,
                const float* __restrict__ rho,
                const float* __restrict__ h0,
                const float* __restrict__ c0,
                const float* __restrict__ W_ih,
                const float* __restrict__ W_hh,
                const float* __restrict__ b_ih,
                const float* __restrict__ b_hh,
                const float* __restrict__ Wp,
                const float* __restrict__ bp,
                float4* __restrict__ mats,      // [BB][S][NQ]
                float* __restrict__ last_bv)
{
  const int b    = blockIdx.x;
  const int tid  = threadIdx.x;
  const int lane = tid & 63;
  const int w    = tid >> 6;

  __shared__ __align__(16) float xh[164];     // x(36) then h(128)
  __shared__ float gbuf[512];
  __shared__ float prj[27];

  // ---- weights into registers (reused all 15 steps)
  float4 wih[9], whh[32];
  {
    const float4* wi = (const float4*)(W_ih + tid*36);
    #pragma unroll
    for (int k = 0; k < 9; ++k) wih[k] = wi[k];
    const float4* wh = (const float4*)(W_hh + tid*H);
    #pragma unroll
    for (int k = 0; k < 32; ++k) whh[k] = wh[k];
  }
  const float bias = b_ih[tid] + b_hh[tid];
  float2 wpv[4]; float bpv[4];
  #pragma unroll
  for (int i = 0; i < 4; ++i) {
    int u = w + 8*i;
    if (u < 27) { wpv[i] = *(const float2*)(Wp + u*H + 2*lane); bpv[i] = bp[u]; }
    else        { wpv[i] = make_float2(0.f, 0.f); bpv[i] = 0.f; }
  }

  // ---- c register-resident on EVERY wave (identical redundant copies)
  float cc0 = c0[b*H + 2*lane], cc1 = c0[b*H + 2*lane + 1];

  // ---- pristine psi0 in wave-0 registers: flat = j*64 + lane
  float pr0[8], pi0[8], norm0 = 0.f;
  if (w == 0) {
    #pragma unroll
    for (int j = 0; j < 8; ++j) {
      pr0[j] = rho[b*1024 + j*64 + lane];
      pi0[j] = rho[b*1024 + 512 + j*64 + lane];
    }
    float ls = 0.f;
    #pragma unroll
    for (int j = 0; j < 8; ++j) ls += pr0[j]*pr0[j] + pi0[j]*pi0[j];
    #pragma unroll
    for (int m = 32; m > 0; m >>= 1) ls += __shfl_xor(ls, m, 64);
    norm0 = ls;
  }

  // ---- init x and h
  if (tid < 128) xh[36 + tid] = h0[b*H + tid];
  if (tid < NQ)  xh[tid]      = snapshot[b*NQ + tid];
  if (tid < 27)  xh[NQ + tid] = bcv[b*27 + tid];
  __syncthreads();

  // t=0 mats from raw inputs
  if (tid < NQ) {
    float s = xh[tid], v0 = xh[9+tid*3], v1 = xh[9+tid*3+1], v2 = xh[9+tid*3+2];
    mats[(b*S + 0)*NQ + tid] = make_float4(
        0.5f*(1.f + 3.f*s*v2), 1.5f*s*v0, -1.5f*s*v1, 0.5f*(1.f - 3.f*s*v2));
  }

  for (int t = 1; t < S; ++t) {
    // ---- gates (all 512 threads, register weights, broadcast LDS reads)
    {
      const float4* x4 = (const float4*)xh;
      float g0 = bias, g1 = 0.f, g2 = 0.f, g3 = 0.f;
      #pragma unroll
      for (int k = 0; k < 9; ++k) {
        float4 wv = wih[k], xv = x4[k];
        g0 += wv.x*xv.x; g1 += wv.y*xv.y; g2 += wv.z*xv.z; g3 += wv.w*xv.w;
      }
      #pragma unroll
      for (int k = 0; k < 32; ++k) {
        float4 wv = whh[k], xv = x4[9 + k];
        g0 += wv.x*xv.x; g1 += wv.y*xv.y; g2 += wv.z*xv.z; g3 += wv.w*xv.w;
      }
      gbuf[tid] = (g0 + g1) + (g2 + g3);
    }
    __syncthreads();                                        // B1

    // ---- cell update: EVERY wave computes h[2*lane], h[2*lane+1] locally
    float h0v, h1v;
    {
      float2 gI = *(const float2*)(gbuf + 2*lane);
      float2 gF = *(const float2*)(gbuf + 128 + 2*lane);
      float2 gG = *(const float2*)(gbuf + 256 + 2*lane);
      float2 gO = *(const float2*)(gbuf + 384 + 2*lane);
      cc0 = sigf(gF.x)*cc0 + sigf(gI.x)*tanhf(gG.x);
      cc1 = sigf(gF.y)*cc1 + sigf(gI.y)*tanhf(gG.y);
      h0v = sigf(gO.x)*tanhf(cc0);
      h1v = sigf(gO.y)*tanhf(cc1);
    }
    if (w == 1) *(float2*)(xh + 36 + 2*lane) = make_float2(h0v, h1v);

    // ---- projection logits: unit u = w + 8i, butterfly within each wave
    #pragma unroll
    for (int i = 0; i < 4; ++i) {
      float p = wpv[i].x*h0v + wpv[i].y*h1v;
      #pragma unroll
      for (int m = 32; m > 0; m >>= 1) p += __shfl_xor(p, m, 64);
      int u = w + 8*i;
      if (u < 27 && lane == 0) prj[u] = p + bpv[i];
    }
    __syncthreads();                                        // B2

    // ---- wave 0: softmax -> amps; deferred-norm collapse; emit
    if (w == 0) {
      float a1 = 0.f, a2 = 0.f, a3 = 0.f;
      if (lane < NQ) {
        float l0 = prj[lane*3], l1 = prj[lane*3+1], l2 = prj[lane*3+2];
        float mx = fmaxf(l0, fmaxf(l1, l2));
        float e0 = __expf(l0 - mx), e1 = __expf(l1 - mx), e2 = __expf(l2 - mx);
        float inv = 1.f/(e0 + e1 + e2);
        a1 = sqrtf(e0*inv); a2 = sqrtf(e1*inv); a3 = sqrtf(e2*inv);
      }
      // precompute conj(p+) coefficients for all 9 qubits (off-chain)
      float K0[9], K1r[9], K1i[9];
      #pragma unroll
      for (int q = 0; q < NQ; ++q) {
        float b1 = __shfl(a1, q, 64), b2 = __shfl(a2, q, 64), b3 = __shfl(a3, q, 64);
        float an = sqrtf(b1*b1 + b2*b2 + b3*b3);
        float t3 = b3 + an;
        float n1 = 1.f/sqrtf(2.f*an*t3);
        K0[q] = n1*t3; K1r[q] = n1*b1; K1i[q] = -n1*b2;
      }
      float Lprev = norm0, sv = 0.f;

      // q0: register bit 2 (no shuffle)
      float r4[4], i4[4];
      {
        float lp = 0.f;
        #pragma unroll
        for (int j = 0; j < 4; ++j) {
          r4[j] = K0[0]*pr0[j] + K1r[0]*pr0[j+4] - K1i[0]*pi0[j+4];
          i4[j] = K0[0]*pi0[j] + K1r[0]*pi0[j+4] + K1i[0]*pr0[j+4];
          lp += r4[j]*r4[j] + i4[j]*i4[j];
        }
        #pragma unroll
        for (int m = 32; m > 0; m >>= 1) lp += __shfl_xor(lp, m, 64);
        if (lane == 0) sv = 2.f*lp - Lprev;
        Lprev = lp;
      }
      // q1: register bit 1
      float r2[2], i2[2];
      {
        float lp = 0.f;
        #pragma unroll
        for (int j = 0; j < 2; ++j) {
          r2[j] = K0[1]*r4[j] + K1r[1]*r4[j+2] - K1i[1]*i4[j+2];
          i2[j] = K0[1]*i4[j] + K1r[1]*i4[j+2] + K1i[1]*r4[j+2];
          lp += r2[j]*r2[j] + i2[j]*i2[j];
        }
        #pragma unroll
        for (int m = 32; m > 0; m >>= 1) lp += __shfl_xor(lp, m, 64);
        if (lane == 1) sv = 2.f*lp/Lprev - 1.f;
        Lprev = lp;
      }
      // q2: register bit 0
      float wr, wi_;
      {
        wr  = K0[2]*r2[0] + K1r[2]*r2[1] - K1i[2]*i2[1];
        wi_ = K0[2]*i2[0] + K1r[2]*i2[1] + K1i[2]*r2[1];
        float lp = wr*wr + wi_*wi_;
        #pragma unroll
        for (int m = 32; m > 0; m >>= 1) lp += __shfl_xor(lp, m, 64);
        if (lane == 2) sv = 2.f*lp/Lprev - 1.f;
        Lprev = lp;
      }
      // q3..q8: lane bits 5..0, one complex value per lane
      #pragma unroll
      for (int q = 3; q < NQ; ++q) {
        const int half = 32 >> (q - 3);
        float pr = __shfl(wr,  lane + half, 64);
        float pi = __shfl(wi_, lane + half, 64);
        float nr = K0[q]*wr  + K1r[q]*pr - K1i[q]*pi;
        float ni = K0[q]*wi_ + K1r[q]*pi + K1i[q]*pr;
        wr = nr; wi_ = ni;
        float lp = (lane < half) ? (nr*nr + ni*ni) : 0.f;
        #pragma unroll
        for (int m = 32; m > 0; m >>= 1) lp += __shfl_xor(lp, m, 64);
        if (lane == q) sv = 2.f*lp/Lprev - 1.f;
        Lprev = lp;
      }
      // emit: new x = [snap, amps] and mats row for this t
      if (lane < NQ) {
        xh[lane] = sv;
        xh[9 + lane*3]     = a1;
        xh[9 + lane*3 + 1] = a2;
        xh[9 + lane*3 + 2] = a3;
        mats[(b*S + t)*NQ + lane] = make_float4(
            0.5f*(1.f + 3.f*sv*a3), 1.5f*sv*a1,
            -1.5f*sv*a2,            0.5f*(1.f - 3.f*sv*a3));
      }
    }
    __syncthreads();                                        // B3
  }

  if (tid < 27) last_bv[b*27 + tid] = xh[9 + tid];
}

// ---------------------------------------------------------------------------
// Kernel 2: out[b] = (1/S) sum_t Top(q0..3,16x16) (x) Bot(q4..8,32x32).
// 4 rows per block, 4 cols per thread: grid (128, 16), float4 stores.
// ---------------------------------------------------------------------------
__device__ __forceinline__ void herm_entry(float4 m, int rb, int cb, float& er, float& ei) {
  if (rb == 0) { if (cb == 0) { er = m.x; ei = 0.f; } else { er = m.y; ei = m.z; } }
  else         { if (cb == 0) { er = m.y; ei = -m.z; } else { er = m.w; ei = 0.f; } }
}

__global__ __launch_bounds__(512, 2)
void kron_kernel(const float4* __restrict__ mats_g, float* __restrict__ out)
{
  const int b   = blockIdx.y;
  const int bm  = blockIdx.x;          // 0..127: rows [4bm, 4bm+4)
  const int tid = threadIdx.x;
  const int rT  = bm >> 3;             // rows share top-row index
  const int rB0 = (bm & 7) << 2;

  __shared__ float4 mats[S*NQ];        // 2.3 KB
  __shared__ float2 top[S*16];         // 2 KB   [t][cT] for this rT
  __shared__ float2 bot[4][S*32];      // 16 KB  [r][t][cB]

  if (tid < S*NQ) mats[tid] = mats_g[b*S*NQ + tid];
  __syncthreads();

  if (tid < 256) {                     // t = tid>>4, cT = tid&15
    int t = tid >> 4, cT = tid & 15;
    float re = 1.f, im = 0.f;
    #pragma unroll
    for (int q = 0; q < 4; ++q) {
      int rb = (rT >> (3 - q)) & 1, cb = (cT >> (3 - q)) & 1;
      float er, ei; herm_entry(mats[t*NQ + q], rb, cb, er, ei);
      float nr = re*er - im*ei; im = re*ei + im*er; re = nr;
    }
    top[tid] = make_float2(re, im);
  }
  {
    const int r_  = tid >> 7;          // 0..3
    const int t_  = (tid >> 3) & 15;
    const int cB0 = (tid & 7) << 2;
    const int rB  = rB0 + r_;
    #pragma unroll
    for (int i = 0; i < 4; ++i) {
      int cB = cB0 + i;
      float re = 1.f, im = 0.f;
      #pragma unroll
      for (int q = 0; q < 5; ++q) {
        int rb = (rB >> (4 - q)) & 1, cb = (cB >> (4 - q)) & 1;
        float er, ei; herm_entry(mats[t_*NQ + 4 + q], rb, cb, er, ei);
        float nr = re*er - im*ei; im = re*ei + im*er; re = nr;
      }
      bot[r_][t_*32 + cB] = make_float2(re, im);
    }
  }
  __syncthreads();

  const int r   = tid >> 7;            // row within block
  const int c0  = (tid & 127) << 2;    // first of 4 consecutive cols
  const int cT  = c0 >> 5;
  const int cB  = c0 & 31;
  float4 ar = make_float4(0.f,0.f,0.f,0.f);
  float4 ai = make_float4(0.f,0.f,0.f,0.f);
  #pragma unroll
  for (int t = 0; t < S; ++t) {
    float2 a  = top[t*16 + cT];
    float2 b0 = bot[r][t*32 + cB];
    float2 b1 = bot[r][t*32 + cB + 1];
    float2 b2 = bot[r][t*32 + cB + 2];
    float2 b3 = bot[r][t*32 + cB + 3];
    ar.x += a.x*b0.x - a.y*b0.y;  ai.x += a.x*b0.y + a.y*b0.x;
    ar.y += a.x*b1.x - a.y*b1.y;  ai.y += a.x*b1.y + a.y*b1.x;
    ar.z += a.x*b2.x - a.y*b2.y;  ai.z += a.x*b2.y + a.y*b2.x;
    ar.w += a.x*b3.x - a.y*b3.y;  ai.w += a.x*b3.y + a.y*b3.x;
  }
  const float invS = 1.f/16.f;
  ar.x *= invS; ar.y *= invS; ar.z *= invS; ar.w *= invS;
  ai.x *= invS; ai.y *= invS; ai.z *= invS; ai.w *= invS;
  const int row = (bm << 2) + r;
  size_t base = ((size_t)b*2)*DD + (size_t)row*D + c0;
  *(float4*)(out + base)      = ar;
  *(float4*)(out + base + DD) = ai;
}

extern "C" void kernel_launch(void* const* d_in, const int* in_sizes, int n_in,
                              void* d_out, int out_size, void* d_ws, size_t ws_size,
                              hipStream_t stream) {
  const float* snapshot = (const float*)d_in[0];
  const float* bcv      = (const float*)d_in[1];
  const float* rho      = (const float*)d_in[2];
  const float* h0       = (const float*)d_in[3];
  const float* c0       = (const float*)d_in[4];
  const float* W_ih     = (const float*)d_in[5];
  const float* W_hh     = (const float*)d_in[6];
  const float* b_ih     = (const float*)d_in[7];
  const float* b_hh     = (const float*)d_in[8];
  const float* Wp       = (const float*)d_in[9];
  const float* bp       = (const float*)d_in[10];

  float*  out     = (float*)d_out;
  float4* mats    = (float4*)d_ws;                 // 16*16*9 float4 = 36 KB
  float*  last_bv = out + (size_t)BB*2*DD;         // output chunk 1

  seq_kernel<<<BB, 512, 0, stream>>>(snapshot, bcv, rho, h0, c0,
                                     W_ih, W_hh, b_ih, b_hh, Wp, bp,
                                     mats, last_bv);

  dim3 grid(128, BB);
  kron_kernel<<<grid, 512, 0, stream>>>(mats, out);
}

// Round 7
// 171.526 us; speedup vs baseline: 2.9233x; 1.3131x over previous
//
#include <hip/hip_runtime.h>
#include <math.h>

#define NQ 9
#define KK 3
#define S 16
#define H 128
#define BB 16
#define D 512
#define DD (D*D)

__device__ __forceinline__ float sigf(float x){ return 1.f/(1.f + __expf(-x)); }

// DPP-based wave(64) sum reduction (AMD cross-lane blog sequence):
// row_shr:1/2/4/8 inclusive scan, row_bcast:15 (rows 1,3), row_bcast:31
// (rows 2,3), total in lane 63. Source lane of row_shr:N is (i-N); invalid
// lanes contribute old=0.
#define DPP_ADD(x, ctrl, rmask) \
  x += __int_as_float(__builtin_amdgcn_update_dpp(0, __float_as_int(x), ctrl, rmask, 0xf, false))

__device__ __forceinline__ float wave_red_sum(float x) {
  DPP_ADD(x, 0x111, 0xf);   // row_shr:1
  DPP_ADD(x, 0x112, 0xf);   // row_shr:2
  DPP_ADD(x, 0x114, 0xf);   // row_shr:4
  DPP_ADD(x, 0x118, 0xf);   // row_shr:8
  DPP_ADD(x, 0x142, 0xa);   // row_bcast:15 -> rows 1,3
  DPP_ADD(x, 0x143, 0xc);   // row_bcast:31 -> rows 2,3
  return __int_as_float(__builtin_amdgcn_readlane(__float_as_int(x), 63));
}
#define RL(v, l) __int_as_float(__builtin_amdgcn_readlane(__float_as_int(v), (l)))
// row_ror:N: source lane = (i - N) mod 16. To read lane (i + half) use
// N = 16 - half.
#define DPP_ROR(x, n) \
  __int_as_float(__builtin_amdgcn_update_dpp(0, __float_as_int(x), 0x120 + (n), 0xf, 0xf, false))

// ---------------------------------------------------------------------------
// Kernel 1: sequential LSTM + snapshot recurrence, fp32, one block/batch
// (512 thr = 8 waves). Weights register-resident. 3 barriers/step.
// Collapse on wave 0: deferred-norm halving contraction. State layout
// flat = j*64 + lane: qubits 0-2 in register bits (no cross-lane), q3/q4 via
// 2 bpermutes, q5-q8 via DPP row_ror (16-half!). Norm reductions batched.
// s_0 = 2L_0 - |psi0|^2 ; s_q = 2 L_q/L_{q-1} - 1 (projector completeness).
// Reference semantics: every timestep's collapse starts from pristine psi0.
// ---------------------------------------------------------------------------
__global__ __launch_bounds__(512, 2)
void seq_kernel(const float* __restrict__ snapshot,
                const float* __restrict__ bcv,
                const float* __restrict__ rho,
                const float* __restrict__ h0,
                const float* __restrict__ c0,
                const float* __restrict__ W_ih,
                const float* __restrict__ W_hh,
                const float* __restrict__ b_ih,
                const float* __restrict__ b_hh,
                const float* __restrict__ Wp,
                const float* __restrict__ bp,
                float4* __restrict__ mats,      // [BB][S][NQ]
                float* __restrict__ last_bv)
{
  const int b    = blockIdx.x;
  const int tid  = threadIdx.x;
  const int lane = tid & 63;
  const int w    = tid >> 6;

  __shared__ __align__(16) float xh[164];     // x(36) then h(128)
  __shared__ float gbuf[512];
  __shared__ float prj[27];

  // ---- weights into registers (reused all 15 steps)
  float4 wih[9], whh[32];
  {
    const float4* wi = (const float4*)(W_ih + tid*36);
    #pragma unroll
    for (int k = 0; k < 9; ++k) wih[k] = wi[k];
    const float4* wh = (const float4*)(W_hh + tid*H);
    #pragma unroll
    for (int k = 0; k < 32; ++k) whh[k] = wh[k];
  }
  const float bias = b_ih[tid] + b_hh[tid];
  float2 wpv[4]; float bpv[4];
  #pragma unroll
  for (int i = 0; i < 4; ++i) {
    int u = w + 8*i;
    if (u < 27) { wpv[i] = *(const float2*)(Wp + u*H + 2*lane); bpv[i] = bp[u]; }
    else        { wpv[i] = make_float2(0.f, 0.f); bpv[i] = 0.f; }
  }

  // ---- c register-resident on EVERY wave (identical redundant copies)
  float cc0 = c0[b*H + 2*lane], cc1 = c0[b*H + 2*lane + 1];

  // ---- pristine psi0 in wave-0 registers: flat = j*64 + lane
  float pr0[8], pi0[8], norm0 = 0.f;
  if (w == 0) {
    #pragma unroll
    for (int j = 0; j < 8; ++j) {
      pr0[j] = rho[b*1024 + j*64 + lane];
      pi0[j] = rho[b*1024 + 512 + j*64 + lane];
    }
    float ls = 0.f;
    #pragma unroll
    for (int j = 0; j < 8; ++j) ls += pr0[j]*pr0[j] + pi0[j]*pi0[j];
    norm0 = wave_red_sum(ls);
  }

  // ---- init x and h
  if (tid < 128) xh[36 + tid] = h0[b*H + tid];
  if (tid < NQ)  xh[tid]      = snapshot[b*NQ + tid];
  if (tid < 27)  xh[NQ + tid] = bcv[b*27 + tid];
  __syncthreads();

  // t=0 mats from raw inputs
  if (tid < NQ) {
    float s = xh[tid], v0 = xh[9+tid*3], v1 = xh[9+tid*3+1], v2 = xh[9+tid*3+2];
    mats[(b*S + 0)*NQ + tid] = make_float4(
        0.5f*(1.f + 3.f*s*v2), 1.5f*s*v0, -1.5f*s*v1, 0.5f*(1.f - 3.f*s*v2));
  }

  for (int t = 1; t < S; ++t) {
    // ---- gates (all 512 threads, register weights, broadcast LDS reads)
    {
      const float4* x4 = (const float4*)xh;
      float g0 = bias, g1 = 0.f, g2 = 0.f, g3 = 0.f;
      #pragma unroll
      for (int k = 0; k < 9; ++k) {
        float4 wv = wih[k], xv = x4[k];
        g0 += wv.x*xv.x; g1 += wv.y*xv.y; g2 += wv.z*xv.z; g3 += wv.w*xv.w;
      }
      #pragma unroll
      for (int k = 0; k < 32; ++k) {
        float4 wv = whh[k], xv = x4[9 + k];
        g0 += wv.x*xv.x; g1 += wv.y*xv.y; g2 += wv.z*xv.z; g3 += wv.w*xv.w;
      }
      gbuf[tid] = (g0 + g1) + (g2 + g3);
    }
    __syncthreads();                                        // B1

    // ---- cell update: EVERY wave computes h[2*lane], h[2*lane+1] locally
    float h0v, h1v;
    {
      float2 gI = *(const float2*)(gbuf + 2*lane);
      float2 gF = *(const float2*)(gbuf + 128 + 2*lane);
      float2 gG = *(const float2*)(gbuf + 256 + 2*lane);
      float2 gO = *(const float2*)(gbuf + 384 + 2*lane);
      cc0 = sigf(gF.x)*cc0 + sigf(gI.x)*tanhf(gG.x);
      cc1 = sigf(gF.y)*cc1 + sigf(gI.y)*tanhf(gG.y);
      h0v = sigf(gO.x)*tanhf(cc0);
      h1v = sigf(gO.y)*tanhf(cc1);
    }
    if (w == 1) *(float2*)(xh + 36 + 2*lane) = make_float2(h0v, h1v);

    // ---- projection logits: unit u = w + 8i, DPP wave reduction
    #pragma unroll
    for (int i = 0; i < 4; ++i) {
      float p = wave_red_sum(wpv[i].x*h0v + wpv[i].y*h1v);
      int u = w + 8*i;
      if (u < 27 && lane == 0) prj[u] = p + bpv[i];
    }
    __syncthreads();                                        // B2

    // ---- wave 0: softmax -> amps; deferred-norm collapse; emit
    if (w == 0) {
      float a1 = 0.f, a2 = 0.f, a3 = 0.f;
      float k0v = 0.f, k1rv = 0.f, k1iv = 0.f;
      if (lane < NQ) {
        float l0 = prj[lane*3], l1 = prj[lane*3+1], l2 = prj[lane*3+2];
        float mx = fmaxf(l0, fmaxf(l1, l2));
        float e0 = __expf(l0 - mx), e1 = __expf(l1 - mx), e2 = __expf(l2 - mx);
        float inv = 1.f/(e0 + e1 + e2);
        a1 = sqrtf(e0*inv); a2 = sqrtf(e1*inv); a3 = sqrtf(e2*inv);
        float an = sqrtf(a1*a1 + a2*a2 + a3*a3);
        float t3 = a3 + an;
        float n1 = 1.f/sqrtf(2.f*an*t3);
        k0v = n1*t3; k1rv = n1*a1; k1iv = -n1*a2;  // conj(p+) coefficients
      }
      float part[9];

      // q0: register bit 2 (no cross-lane)
      float r4[4], i4[4];
      {
        const float K0 = RL(k0v,0), K1r = RL(k1rv,0), K1i = RL(k1iv,0);
        float lp = 0.f;
        #pragma unroll
        for (int j = 0; j < 4; ++j) {
          r4[j] = K0*pr0[j] + K1r*pr0[j+4] - K1i*pi0[j+4];
          i4[j] = K0*pi0[j] + K1r*pi0[j+4] + K1i*pr0[j+4];
          lp += r4[j]*r4[j] + i4[j]*i4[j];
        }
        part[0] = lp;
      }
      // q1: register bit 1
      float r2[2], i2[2];
      {
        const float K0 = RL(k0v,1), K1r = RL(k1rv,1), K1i = RL(k1iv,1);
        float lp = 0.f;
        #pragma unroll
        for (int j = 0; j < 2; ++j) {
          r2[j] = K0*r4[j] + K1r*r4[j+2] - K1i*i4[j+2];
          i2[j] = K0*i4[j] + K1r*i4[j+2] + K1i*r4[j+2];
          lp += r2[j]*r2[j] + i2[j]*i2[j];
        }
        part[1] = lp;
      }
      // q2: register bit 0
      float wr, wi_;
      {
        const float K0 = RL(k0v,2), K1r = RL(k1rv,2), K1i = RL(k1iv,2);
        wr  = K0*r2[0] + K1r*r2[1] - K1i*i2[1];
        wi_ = K0*i2[0] + K1r*i2[1] + K1i*r2[1];
        part[2] = wr*wr + wi_*wi_;
      }
      // q3, q4: partner lane+half via bpermute (half = 32, 16)
      #pragma unroll
      for (int q = 3; q < 5; ++q) {
        const int half = 32 >> (q - 3);
        const float K0 = RL(k0v,q), K1r = RL(k1rv,q), K1i = RL(k1iv,q);
        float pr = __shfl(wr,  lane + half, 64);
        float pi = __shfl(wi_, lane + half, 64);
        float nr = K0*wr  + K1r*pr - K1i*pi;
        float ni = K0*wi_ + K1r*pi + K1i*pr;
        wr = nr; wi_ = ni;
        part[q] = (lane < half) ? (nr*nr + ni*ni) : 0.f;
      }
      // q5..q8: partner lane+half via row_ror:(16-half)  [source = i+half]
      // half = 8 -> ror:8, 4 -> ror:12, 2 -> ror:14, 1 -> ror:15
      #pragma unroll
      for (int q = 5; q < NQ; ++q) {
        const int half = 32 >> (q - 3);
        const float K0 = RL(k0v,q), K1r = RL(k1rv,q), K1i = RL(k1iv,q);
        float pr, pi;
        if      (q == 5) { pr = DPP_ROR(wr, 8);  pi = DPP_ROR(wi_, 8);  }
        else if (q == 6) { pr = DPP_ROR(wr, 12); pi = DPP_ROR(wi_, 12); }
        else if (q == 7) { pr = DPP_ROR(wr, 14); pi = DPP_ROR(wi_, 14); }
        else             { pr = DPP_ROR(wr, 15); pi = DPP_ROR(wi_, 15); }
        float nr = K0*wr  + K1r*pr - K1i*pi;
        float ni = K0*wi_ + K1r*pi + K1i*pr;
        wr = nr; wi_ = ni;
        part[q] = (lane < half) ? (nr*nr + ni*ni) : 0.f;
      }
      // batch the 9 norm reductions (independent DPP chains, off main chain)
      float L[9];
      #pragma unroll
      for (int q = 0; q < NQ; ++q) L[q] = wave_red_sum(part[q]);
      // s values (uniform math, then per-lane select)
      float sv = 2.f*L[0] - norm0;
      #pragma unroll
      for (int q = 1; q < NQ; ++q) {
        float r = 2.f*L[q]/L[q-1] - 1.f;
        sv = (lane == q) ? r : sv;
      }
      // emit: new x = [snap, amps] and mats row for this t
      if (lane < NQ) {
        xh[lane] = sv;
        xh[9 + lane*3]     = a1;
        xh[9 + lane*3 + 1] = a2;
        xh[9 + lane*3 + 2] = a3;
        mats[(b*S + t)*NQ + lane] = make_float4(
            0.5f*(1.f + 3.f*sv*a3), 1.5f*sv*a1,
            -1.5f*sv*a2,            0.5f*(1.f - 3.f*sv*a3));
      }
    }
    __syncthreads();                                        // B3
  }

  if (tid < 27) last_bv[b*27 + tid] = xh[9 + tid];
}

// ---------------------------------------------------------------------------
// Kernel 2: out[b] = (1/S) sum_t Top(q0..3,16x16) (x) Bot(q4..8,32x32).
// Block covers 2 rT x 4 rB rows (bot reads amortized over 2 output rows).
// grid (64, 16) = 1024 blocks. b128 bot reads, float4 stores.
// ---------------------------------------------------------------------------
__device__ __forceinline__ void herm_entry(float4 m, int rb, int cb, float& er, float& ei) {
  if (rb == 0) { if (cb == 0) { er = m.x; ei = 0.f; } else { er = m.y; ei = m.z; } }
  else         { if (cb == 0) { er = m.y; ei = -m.z; } else { er = m.w; ei = 0.f; } }
}

__global__ __launch_bounds__(512, 2)
void kron_kernel(const float4* __restrict__ mats_g, float* __restrict__ out)
{
  const int b   = blockIdx.y;
  const int bm  = blockIdx.x;          // rTp = bm>>3 (rT pair), rg = bm&7 (rB grp)
  const int tid = threadIdx.x;
  const int rTp = bm >> 3;
  const int rg  = bm & 7;

  __shared__ float4 matsh[S*NQ];           // 2.3 KB
  __shared__ float2 top[S][2][16];         // 4 KB   [t][rTi][cT]
  __shared__ __align__(16) float2 bot[4][S][32];  // 16 KB  [r][t][cB]

  if (tid < S*NQ) matsh[tid] = mats_g[b*S*NQ + tid];
  __syncthreads();

  {                                    // top: 512 entries, one per thread
    int t = tid >> 5, rTi = (tid >> 4) & 1, cT = tid & 15;
    int rT = rTp*2 + rTi;
    float re = 1.f, im = 0.f;
    #pragma unroll
    for (int q = 0; q < 4; ++q) {
      int rb = (rT >> (3 - q)) & 1, cb = (cT >> (3 - q)) & 1;
      float er, ei; herm_entry(matsh[t*NQ + q], rb, cb, er, ei);
      float nr = re*er - im*ei; im = re*ei + im*er; re = nr;
    }
    top[t][rTi][cT] = make_float2(re, im);
  }
  {                                    // bot: 4 entries per thread
    int r_ = tid >> 7, t_ = (tid >> 3) & 15, cB0 = (tid & 7) << 2;
    int rB = rg*4 + r_;
    #pragma unroll
    for (int i = 0; i < 4; ++i) {
      int cB = cB0 + i;
      float re = 1.f, im = 0.f;
      #pragma unroll
      for (int q = 0; q < 5; ++q) {
        int rb = (rB >> (4 - q)) & 1, cb = (cB >> (4 - q)) & 1;
        float er, ei; herm_entry(matsh[t_*NQ + 4 + q], rb, cb, er, ei);
        float nr = re*er - im*ei; im = re*ei + im*er; re = nr;
      }
      bot[r_][t_][cB] = make_float2(re, im);
    }
  }
  __syncthreads();

  const int rb = tid >> 7;             // rB index within block (0..3)
  const int c0 = (tid & 127) << 2;     // 4 consecutive cols
  const int cT = c0 >> 5, cB = c0 & 31;
  float4 a0r = make_float4(0,0,0,0), a0i = make_float4(0,0,0,0);
  float4 a1r = make_float4(0,0,0,0), a1i = make_float4(0,0,0,0);
  #pragma unroll
  for (int t = 0; t < S; ++t) {
    float4 b01 = *(const float4*)&bot[rb][t][cB];      // cols cB, cB+1
    float4 b23 = *(const float4*)&bot[rb][t][cB + 2];  // cols cB+2, cB+3
    float2 tA = top[t][0][cT];
    float2 tB = top[t][1][cT];
    a0r.x += tA.x*b01.x - tA.y*b01.y;  a0i.x += tA.x*b01.y + tA.y*b01.x;
    a0r.y += tA.x*b01.z - tA.y*b01.w;  a0i.y += tA.x*b01.w + tA.y*b01.z;
    a0r.z += tA.x*b23.x - tA.y*b23.y;  a0i.z += tA.x*b23.y + tA.y*b23.x;
    a0r.w += tA.x*b23.z - tA.y*b23.w;  a0i.w += tA.x*b23.w + tA.y*b23.z;
    a1r.x += tB.x*b01.x - tB.y*b01.y;  a1i.x += tB.x*b01.y + tB.y*b01.x;
    a1r.y += tB.x*b01.z - tB.y*b01.w;  a1i.y += tB.x*b01.w + tB.y*b01.z;
    a1r.z += tB.x*b23.x - tB.y*b23.y;  a1i.z += tB.x*b23.y + tB.y*b23.x;
    a1r.w += tB.x*b23.z - tB.y*b23.w;  a1i.w += tB.x*b23.w + tB.y*b23.z;
  }
  const float invS = 1.f/16.f;
  a0r.x*=invS; a0r.y*=invS; a0r.z*=invS; a0r.w*=invS;
  a0i.x*=invS; a0i.y*=invS; a0i.z*=invS; a0i.w*=invS;
  a1r.x*=invS; a1r.y*=invS; a1r.z*=invS; a1r.w*=invS;
  a1i.x*=invS; a1i.y*=invS; a1i.z*=invS; a1i.w*=invS;
  const int rowA = (rTp*2)*32 + rg*4 + rb;   // rT = 2*rTp
  const int rowB = rowA + 32;                // rT = 2*rTp + 1
  size_t baseA = ((size_t)b*2)*DD + (size_t)rowA*D + c0;
  size_t baseB = ((size_t)b*2)*DD + (size_t)rowB*D + c0;
  *(float4*)(out + baseA)      = a0r;
  *(float4*)(out + baseA + DD) = a0i;
  *(float4*)(out + baseB)      = a1r;
  *(float4*)(out + baseB + DD) = a1i;
}

extern "C" void kernel_launch(void* const* d_in, const int* in_sizes, int n_in,
                              void* d_out, int out_size, void* d_ws, size_t ws_size,
                              hipStream_t stream) {
  const float* snapshot = (const float*)d_in[0];
  const float* bcv      = (const float*)d_in[1];
  const float* rho      = (const float*)d_in[2];
  const float* h0       = (const float*)d_in[3];
  const float* c0       = (const float*)d_in[4];
  const float* W_ih     = (const float*)d_in[5];
  const float* W_hh     = (const float*)d_in[6];
  const float* b_ih     = (const float*)d_in[7];
  const float* b_hh     = (const float*)d_in[8];
  const float* Wp       = (const float*)d_in[9];
  const float* bp       = (const float*)d_in[10];

  float*  out     = (float*)d_out;
  float4* mats    = (float4*)d_ws;                 // 16*16*9 float4 = 36 KB
  float*  last_bv = out + (size_t)BB*2*DD;         // output chunk 1

  seq_kernel<<<BB, 512, 0, stream>>>(snapshot, bcv, rho, h0, c0,
                                     W_ih, W_hh, b_ih, b_hh, Wp, bp,
                                     mats, last_bv);

  dim3 grid(64, BB);
  kron_kernel<<<grid, 512, 0, stream>>>(mats, out);
}

// Round 8
// 159.678 us; speedup vs baseline: 3.1402x; 1.0742x over previous
//
#include <hip/hip_runtime.h>
#include <math.h>

#define NQ 9
#define KK 3
#define S 16
#define H 128
#define BB 16
#define D 512
#define DD (D*D)

__device__ __forceinline__ float sigf(float x){ return 1.f/(1.f + __expf(-x)); }

// DPP-based wave(64) sum reduction (AMD cross-lane sequence): row_shr:1/2/4/8
// inclusive scan, row_bcast:15 (rows 1,3), row_bcast:31 (rows 2,3), total in
// lane 63.
#define DPP_ADD(x, ctrl, rmask) \
  x += __int_as_float(__builtin_amdgcn_update_dpp(0, __float_as_int(x), ctrl, rmask, 0xf, false))

__device__ __forceinline__ float wave_red_sum(float x) {
  DPP_ADD(x, 0x111, 0xf);   // row_shr:1
  DPP_ADD(x, 0x112, 0xf);   // row_shr:2
  DPP_ADD(x, 0x114, 0xf);   // row_shr:4
  DPP_ADD(x, 0x118, 0xf);   // row_shr:8
  DPP_ADD(x, 0x142, 0xa);   // row_bcast:15 -> rows 1,3
  DPP_ADD(x, 0x143, 0xc);   // row_bcast:31 -> rows 2,3
  return __int_as_float(__builtin_amdgcn_readlane(__float_as_int(x), 63));
}
#define RL(v, l) __int_as_float(__builtin_amdgcn_readlane(__float_as_int(v), (l)))
// row_ror:N: source lane = (i - N) mod 16. To read lane (i + half) use 16-half.
#define DPP_ROR(x, n) \
  __int_as_float(__builtin_amdgcn_update_dpp(0, __float_as_int(x), 0x120 + (n), 0xf, 0xf, false))

// ---------------------------------------------------------------------------
// Kernel 1: sequential LSTM + snapshot recurrence, fp32, one block/batch
// (512 thr = 8 waves). Weights register-resident. 3+1 barriers/step.
// NEW vs R7:
//  - W_hh*h computed from REGISTER h via v_readlane broadcasts (every wave
//    holds full h redundantly: h[2l],h[2l+1] per lane) -> zero LDS traffic
//    for the big GEMV part, no lgkmcnt drain at barriers.
//  - ghh for step t+1 is computed at the END of step t: waves 1-7 run it
//    WHILE wave 0 runs the collapse (exec-masked overlap); wave 0 appends
//    its own ghh after the collapse. x-part (9 LDS reads) finishes at the
//    top of the next step.
// Collapse (R7-verbatim): deferred-norm halving contraction; qubits 0-2 in
// register bits, q3/q4 via bpermute, q5-q8 via DPP row_ror(16-half);
// s_0 = 2L_0 - |psi0|^2 ; s_q = 2 L_q/L_{q-1} - 1.
// Reference semantics: every timestep's collapse starts from pristine psi0.
// ---------------------------------------------------------------------------
__global__ __launch_bounds__(512, 2)
void seq_kernel(const float* __restrict__ snapshot,
                const float* __restrict__ bcv,
                const float* __restrict__ rho,
                const float* __restrict__ h0,
                const float* __restrict__ c0,
                const float* __restrict__ W_ih,
                const float* __restrict__ W_hh,
                const float* __restrict__ b_ih,
                const float* __restrict__ b_hh,
                const float* __restrict__ Wp,
                const float* __restrict__ bp,
                float4* __restrict__ mats,      // [BB][S][NQ]
                float* __restrict__ last_bv)
{
  const int b    = blockIdx.x;
  const int tid  = threadIdx.x;
  const int lane = tid & 63;
  const int w    = tid >> 6;

  __shared__ __align__(16) float xh[36];      // x only: snap(9) + amps(27)
  __shared__ float gbuf[512];
  __shared__ float prj[27];

  // ---- weights into registers (reused all 15 steps)
  float4 wih[9], whh[32];
  {
    const float4* wi = (const float4*)(W_ih + tid*36);
    #pragma unroll
    for (int k = 0; k < 9; ++k) wih[k] = wi[k];
    const float4* wh = (const float4*)(W_hh + tid*H);
    #pragma unroll
    for (int k = 0; k < 32; ++k) whh[k] = wh[k];
  }
  const float bias = b_ih[tid] + b_hh[tid];
  float2 wpv[4]; float bpv[4];
  #pragma unroll
  for (int i = 0; i < 4; ++i) {
    int u = w + 8*i;
    if (u < 27) { wpv[i] = *(const float2*)(Wp + u*H + 2*lane); bpv[i] = bp[u]; }
    else        { wpv[i] = make_float2(0.f, 0.f); bpv[i] = 0.f; }
  }

  // ---- c and h register-resident on EVERY wave (redundant copies, 2/lane)
  float cc0 = c0[b*H + 2*lane], cc1 = c0[b*H + 2*lane + 1];
  float h0v = h0[b*H + 2*lane], h1v = h0[b*H + 2*lane + 1];

  // ---- pristine psi0 in wave-0 registers: flat = j*64 + lane
  float pr0[8], pi0[8], norm0 = 0.f;
  if (w == 0) {
    #pragma unroll
    for (int j = 0; j < 8; ++j) {
      pr0[j] = rho[b*1024 + j*64 + lane];
      pi0[j] = rho[b*1024 + 512 + j*64 + lane];
    }
    float ls = 0.f;
    #pragma unroll
    for (int j = 0; j < 8; ++j) ls += pr0[j]*pr0[j] + pi0[j]*pi0[j];
    norm0 = wave_red_sum(ls);
  }

  // ---- init x in LDS; t=0 mats straight from global inputs
  if (tid < NQ)  xh[tid]      = snapshot[b*NQ + tid];
  if (tid < 27)  xh[NQ + tid] = bcv[b*27 + tid];
  if (tid < NQ) {
    float s  = snapshot[b*NQ + tid];
    float v0 = bcv[b*27 + tid*3];
    float v1 = bcv[b*27 + tid*3 + 1];
    float v2 = bcv[b*27 + tid*3 + 2];
    mats[(b*S + 0)*NQ + tid] = make_float4(
        0.5f*(1.f + 3.f*s*v2), 1.5f*s*v0, -1.5f*s*v1, 0.5f*(1.f - 3.f*s*v2));
  }

  // ---- pre-loop ghh from h0 registers (readlane broadcast, no LDS)
  float ghh = bias;
  #pragma unroll
  for (int j = 0; j < 32; ++j) {
    float4 wv = whh[j];
    ghh += wv.x*RL(h0v, 2*j)     + wv.y*RL(h1v, 2*j)
         + wv.z*RL(h0v, 2*j + 1) + wv.w*RL(h1v, 2*j + 1);
  }
  __syncthreads();                                        // B0: xh ready

  for (int t = 1; t < S; ++t) {
    // ---- X: finish gates = ghh + W_ih * x   (9 LDS b128 reads)
    {
      const float4* x4 = (const float4*)xh;
      float g0 = ghh, g1 = 0.f, g2 = 0.f, g3 = 0.f;
      #pragma unroll
      for (int k = 0; k < 9; ++k) {
        float4 wv = wih[k], xv = x4[k];
        g0 += wv.x*xv.x; g1 += wv.y*xv.y; g2 += wv.z*xv.z; g3 += wv.w*xv.w;
      }
      gbuf[tid] = (g0 + g1) + (g2 + g3);
    }
    __syncthreads();                                      // B1: gbuf ready

    // ---- C: cell update, every wave redundantly (h in registers)
    {
      float2 gI = *(const float2*)(gbuf + 2*lane);
      float2 gF = *(const float2*)(gbuf + 128 + 2*lane);
      float2 gG = *(const float2*)(gbuf + 256 + 2*lane);
      float2 gO = *(const float2*)(gbuf + 384 + 2*lane);
      cc0 = sigf(gF.x)*cc0 + sigf(gI.x)*tanhf(gG.x);
      cc1 = sigf(gF.y)*cc1 + sigf(gI.y)*tanhf(gG.y);
      h0v = sigf(gO.x)*tanhf(cc0);
      h1v = sigf(gO.y)*tanhf(cc1);
    }
    // ---- projection logits: unit u = w + 8i, DPP wave reduction (reg h)
    #pragma unroll
    for (int i = 0; i < 4; ++i) {
      float p = wave_red_sum(wpv[i].x*h0v + wpv[i].y*h1v);
      int u = w + 8*i;
      if (u < 27 && lane == 0) prj[u] = p + bpv[i];
    }
    __syncthreads();                                      // B2: prj ready

    // ---- wave 0: softmax -> amps; deferred-norm collapse; emit
    //      (waves 1-7 skip straight to the ghh below -> overlap)
    if (w == 0) {
      float a1 = 0.f, a2 = 0.f, a3 = 0.f;
      float k0v = 0.f, k1rv = 0.f, k1iv = 0.f;
      if (lane < NQ) {
        float l0 = prj[lane*3], l1 = prj[lane*3+1], l2 = prj[lane*3+2];
        float mx = fmaxf(l0, fmaxf(l1, l2));
        float e0 = __expf(l0 - mx), e1 = __expf(l1 - mx), e2 = __expf(l2 - mx);
        float inv = 1.f/(e0 + e1 + e2);
        a1 = sqrtf(e0*inv); a2 = sqrtf(e1*inv); a3 = sqrtf(e2*inv);
        float an = sqrtf(a1*a1 + a2*a2 + a3*a3);
        float t3 = a3 + an;
        float n1 = 1.f/sqrtf(2.f*an*t3);
        k0v = n1*t3; k1rv = n1*a1; k1iv = -n1*a2;  // conj(p+) coefficients
      }
      float part[9];

      // q0: register bit 2 (no cross-lane)
      float r4[4], i4[4];
      {
        const float K0 = RL(k0v,0), K1r = RL(k1rv,0), K1i = RL(k1iv,0);
        float lp = 0.f;
        #pragma unroll
        for (int j = 0; j < 4; ++j) {
          r4[j] = K0*pr0[j] + K1r*pr0[j+4] - K1i*pi0[j+4];
          i4[j] = K0*pi0[j] + K1r*pi0[j+4] + K1i*pr0[j+4];
          lp += r4[j]*r4[j] + i4[j]*i4[j];
        }
        part[0] = lp;
      }
      // q1: register bit 1
      float r2[2], i2[2];
      {
        const float K0 = RL(k0v,1), K1r = RL(k1rv,1), K1i = RL(k1iv,1);
        float lp = 0.f;
        #pragma unroll
        for (int j = 0; j < 2; ++j) {
          r2[j] = K0*r4[j] + K1r*r4[j+2] - K1i*i4[j+2];
          i2[j] = K0*i4[j] + K1r*i4[j+2] + K1i*r4[j+2];
          lp += r2[j]*r2[j] + i2[j]*i2[j];
        }
        part[1] = lp;
      }
      // q2: register bit 0
      float wr, wi_;
      {
        const float K0 = RL(k0v,2), K1r = RL(k1rv,2), K1i = RL(k1iv,2);
        wr  = K0*r2[0] + K1r*r2[1] - K1i*i2[1];
        wi_ = K0*i2[0] + K1r*i2[1] + K1i*r2[1];
        part[2] = wr*wr + wi_*wi_;
      }
      // q3, q4: partner lane+half via bpermute (half = 32, 16)
      #pragma unroll
      for (int q = 3; q < 5; ++q) {
        const int half = 32 >> (q - 3);
        const float K0 = RL(k0v,q), K1r = RL(k1rv,q), K1i = RL(k1iv,q);
        float pr = __shfl(wr,  lane + half, 64);
        float pi = __shfl(wi_, lane + half, 64);
        float nr = K0*wr  + K1r*pr - K1i*pi;
        float ni = K0*wi_ + K1r*pi + K1i*pr;
        wr = nr; wi_ = ni;
        part[q] = (lane < half) ? (nr*nr + ni*ni) : 0.f;
      }
      // q5..q8: partner lane+half via row_ror:(16-half)  [source = i+half]
      #pragma unroll
      for (int q = 5; q < NQ; ++q) {
        const int half = 32 >> (q - 3);
        const float K0 = RL(k0v,q), K1r = RL(k1rv,q), K1i = RL(k1iv,q);
        float pr, pi;
        if      (q == 5) { pr = DPP_ROR(wr, 8);  pi = DPP_ROR(wi_, 8);  }
        else if (q == 6) { pr = DPP_ROR(wr, 12); pi = DPP_ROR(wi_, 12); }
        else if (q == 7) { pr = DPP_ROR(wr, 14); pi = DPP_ROR(wi_, 14); }
        else             { pr = DPP_ROR(wr, 15); pi = DPP_ROR(wi_, 15); }
        float nr = K0*wr  + K1r*pr - K1i*pi;
        float ni = K0*wi_ + K1r*pi + K1i*pr;
        wr = nr; wi_ = ni;
        part[q] = (lane < half) ? (nr*nr + ni*ni) : 0.f;
      }
      // batched norm reductions (independent DPP chains)
      float L[9];
      #pragma unroll
      for (int q = 0; q < NQ; ++q) L[q] = wave_red_sum(part[q]);
      float sv = 2.f*L[0] - norm0;
      #pragma unroll
      for (int q = 1; q < NQ; ++q) {
        float r = 2.f*L[q]/L[q-1] - 1.f;
        sv = (lane == q) ? r : sv;
      }
      // emit: new x = [snap, amps] and mats row for this t
      if (lane < NQ) {
        xh[lane] = sv;
        xh[9 + lane*3]     = a1;
        xh[9 + lane*3 + 1] = a2;
        xh[9 + lane*3 + 2] = a3;
        mats[(b*S + t)*NQ + lane] = make_float4(
            0.5f*(1.f + 3.f*sv*a3), 1.5f*sv*a1,
            -1.5f*sv*a2,            0.5f*(1.f - 3.f*sv*a3));
      }
    }

    // ---- ghh for next step from register h (waves 1-7 run this during
    //      wave 0's collapse; wave 0 appends it after)
    if (t < S - 1) {
      float g = bias;
      #pragma unroll
      for (int j = 0; j < 32; ++j) {
        float4 wv = whh[j];
        g += wv.x*RL(h0v, 2*j)     + wv.y*RL(h1v, 2*j)
           + wv.z*RL(h0v, 2*j + 1) + wv.w*RL(h1v, 2*j + 1);
      }
      ghh = g;
    }
    __syncthreads();                                      // B3: xh ready
  }

  if (tid < 27) last_bv[b*27 + tid] = xh[9 + tid];
}

// ---------------------------------------------------------------------------
// Kernel 2: out[b] = (1/S) sum_t Top(q0..3,16x16) (x) Bot(q4..8,32x32).
// v4: block covers 4 rT x 4 rB rows; thread computes 4 rT x 4 cols = 16
// outputs (4 B LDS read per output per t). grid (32, 16) = 512 blocks.
// ---------------------------------------------------------------------------
__device__ __forceinline__ void herm_entry(float4 m, int rb, int cb, float& er, float& ei) {
  if (rb == 0) { if (cb == 0) { er = m.x; ei = 0.f; } else { er = m.y; ei = m.z; } }
  else         { if (cb == 0) { er = m.y; ei = -m.z; } else { er = m.w; ei = 0.f; } }
}

__global__ __launch_bounds__(512, 2)
void kron_kernel(const float4* __restrict__ mats_g, float* __restrict__ out)
{
  const int b   = blockIdx.y;
  const int bm  = blockIdx.x;
  const int tid = threadIdx.x;
  const int rTg = bm >> 3;             // [0,4): rT = 4*rTg + i
  const int rBg = bm & 7;              // [0,8): rB = 4*rBg + r

  __shared__ float4 matsh[S*NQ];                  // 2.3 KB
  __shared__ float2 top[S][4][16];                // 8 KB  [t][rTi][cT]
  __shared__ __align__(16) float2 bot[4][S][32];  // 16 KB [r][t][cB]

  if (tid < S*NQ) matsh[tid] = mats_g[b*S*NQ + tid];
  __syncthreads();

  // top staging: 1024 entries, 2 per thread
  #pragma unroll
  for (int e = tid; e < 1024; e += 512) {
    int t = e >> 6, rTi = (e >> 4) & 3, cT = e & 15;
    int rT = rTg*4 + rTi;
    float re = 1.f, im = 0.f;
    #pragma unroll
    for (int q = 0; q < 4; ++q) {
      int rb = (rT >> (3 - q)) & 1, cb = (cT >> (3 - q)) & 1;
      float er, ei; herm_entry(matsh[t*NQ + q], rb, cb, er, ei);
      float nr = re*er - im*ei; im = re*ei + im*er; re = nr;
    }
    top[t][rTi][cT] = make_float2(re, im);
  }
  // bot staging: 2048 entries, 4 contiguous per thread
  {
    int e0 = tid*4;
    int r_ = e0 >> 9, t_ = (e0 >> 5) & 15, cB0 = e0 & 31;
    int rB = rBg*4 + r_;
    #pragma unroll
    for (int i = 0; i < 4; ++i) {
      int cB = cB0 + i;
      float re = 1.f, im = 0.f;
      #pragma unroll
      for (int q = 0; q < 5; ++q) {
        int rb = (rB >> (4 - q)) & 1, cb = (cB >> (4 - q)) & 1;
        float er, ei; herm_entry(matsh[t_*NQ + 4 + q], rb, cb, er, ei);
        float nr = re*er - im*ei; im = re*ei + im*er; re = nr;
      }
      bot[r_][t_][cB] = make_float2(re, im);
    }
  }
  __syncthreads();

  const int rb = tid >> 7;             // [0,4): rB row within block
  const int c0 = (tid & 127) << 2;     // 4 consecutive cols
  const int cT = c0 >> 5, cB = c0 & 31;
  float4 accr[4], acci[4];             // [rTi]
  #pragma unroll
  for (int i = 0; i < 4; ++i) {
    accr[i] = make_float4(0.f,0.f,0.f,0.f);
    acci[i] = make_float4(0.f,0.f,0.f,0.f);
  }
  #pragma unroll
  for (int t = 0; t < S; ++t) {
    float4 b01 = *(const float4*)&bot[rb][t][cB];      // cols cB, cB+1
    float4 b23 = *(const float4*)&bot[rb][t][cB + 2];  // cols cB+2, cB+3
    #pragma unroll
    for (int i = 0; i < 4; ++i) {
      float2 tv = top[t][i][cT];
      accr[i].x += tv.x*b01.x - tv.y*b01.y;  acci[i].x += tv.x*b01.y + tv.y*b01.x;
      accr[i].y += tv.x*b01.z - tv.y*b01.w;  acci[i].y += tv.x*b01.w + tv.y*b01.z;
      accr[i].z += tv.x*b23.x - tv.y*b23.y;  acci[i].z += tv.x*b23.y + tv.y*b23.x;
      accr[i].w += tv.x*b23.z - tv.y*b23.w;  acci[i].w += tv.x*b23.w + tv.y*b23.z;
    }
  }
  const float invS = 1.f/16.f;
  #pragma unroll
  for (int i = 0; i < 4; ++i) {
    accr[i].x*=invS; accr[i].y*=invS; accr[i].z*=invS; accr[i].w*=invS;
    acci[i].x*=invS; acci[i].y*=invS; acci[i].z*=invS; acci[i].w*=invS;
    int row = (rTg*4 + i)*32 + rBg*4 + rb;
    size_t base = ((size_t)b*2)*DD + (size_t)row*D + c0;
    *(float4*)(out + base)      = accr[i];
    *(float4*)(out + base + DD) = acci[i];
  }
}

extern "C" void kernel_launch(void* const* d_in, const int* in_sizes, int n_in,
                              void* d_out, int out_size, void* d_ws, size_t ws_size,
                              hipStream_t stream) {
  const float* snapshot = (const float*)d_in[0];
  const float* bcv      = (const float*)d_in[1];
  const float* rho      = (const float*)d_in[2];
  const float* h0       = (const float*)d_in[3];
  const float* c0       = (const float*)d_in[4];
  const float* W_ih     = (const float*)d_in[5];
  const float* W_hh     = (const float*)d_in[6];
  const float* b_ih     = (const float*)d_in[7];
  const float* b_hh     = (const float*)d_in[8];
  const float* Wp       = (const float*)d_in[9];
  const float* bp       = (const float*)d_in[10];

  float*  out     = (float*)d_out;
  float4* mats    = (float4*)d_ws;                 // 16*16*9 float4 = 36 KB
  float*  last_bv = out + (size_t)BB*2*DD;         // output chunk 1

  seq_kernel<<<BB, 512, 0, stream>>>(snapshot, bcv, rho, h0, c0,
                                     W_ih, W_hh, b_ih, b_hh, Wp, bp,
                                     mats, last_bv);

  dim3 grid(32, BB);
  kron_kernel<<<grid, 512, 0, stream>>>(mats, out);
}

// Round 10
// 155.384 us; speedup vs baseline: 3.2270x; 1.0276x over previous
//
#include <hip/hip_runtime.h>
#include <math.h>

#define NQ 9
#define KK 3
#define S 16
#define H 128
#define BB 16
#define D 512
#define DD (D*D)

typedef float vfloat4 __attribute__((ext_vector_type(4)));  // native vec for nontemporal

__device__ __forceinline__ float sigf(float x){ return 1.f/(1.f + __expf(-x)); }
// fast tanh: 1 - 2/(e^{2x}+1); exact at +-inf saturation, ~1ulp interior
__device__ __forceinline__ float tanhfast(float x){
  float e = __expf(2.f*x);
  return 1.f - 2.f/(e + 1.f);
}
#define RCP(x)  __builtin_amdgcn_rcpf(x)
#define RSQ(x)  __builtin_amdgcn_rsqf(x)

// DPP-based wave(64) sum reduction (AMD cross-lane sequence): row_shr:1/2/4/8
// inclusive scan, row_bcast:15 (rows 1,3), row_bcast:31 (rows 2,3), total in
// lane 63.
#define DPP_ADD(x, ctrl, rmask) \
  x += __int_as_float(__builtin_amdgcn_update_dpp(0, __float_as_int(x), ctrl, rmask, 0xf, false))

__device__ __forceinline__ float wave_red_sum(float x) {
  DPP_ADD(x, 0x111, 0xf);   // row_shr:1
  DPP_ADD(x, 0x112, 0xf);   // row_shr:2
  DPP_ADD(x, 0x114, 0xf);   // row_shr:4
  DPP_ADD(x, 0x118, 0xf);   // row_shr:8
  DPP_ADD(x, 0x142, 0xa);   // row_bcast:15 -> rows 1,3
  DPP_ADD(x, 0x143, 0xc);   // row_bcast:31 -> rows 2,3
  return __int_as_float(__builtin_amdgcn_readlane(__float_as_int(x), 63));
}
#define RL(v, l) __int_as_float(__builtin_amdgcn_readlane(__float_as_int(v), (l)))
// row_ror:N: source lane = (i - N) mod 16. To read lane (i + half) use 16-half.
#define DPP_ROR(x, n) \
  __int_as_float(__builtin_amdgcn_update_dpp(0, __float_as_int(x), 0x120 + (n), 0xf, 0xf, false))

// ---------------------------------------------------------------------------
// Kernel 1: sequential LSTM + snapshot recurrence, fp32, one block/batch
// (512 thr = 8 waves). Weights register-resident; W_hh*h via v_readlane
// broadcasts from register h (every wave holds full h redundantly); ghh for
// step t+1 computed by waves 1-7 WHILE wave 0 runs the collapse.
// Collapse: deferred-norm halving contraction; qubits 0-2 in register bits,
// q3/q4 via bpermute, q5-q8 via DPP row_ror(16-half);
// s_0 = 2L_0 - |psi0|^2 ; s_q = 2 L_q/L_{q-1} - 1 (projector completeness).
// Reference semantics: every timestep's collapse starts from pristine psi0.
// ---------------------------------------------------------------------------
__global__ __launch_bounds__(512, 2)
void seq_kernel(const float* __restrict__ snapshot,
                const float* __restrict__ bcv,
                const float* __restrict__ rho,
                const float* __restrict__ h0,
                const float* __restrict__ c0,
                const float* __restrict__ W_ih,
                const float* __restrict__ W_hh,
                const float* __restrict__ b_ih,
                const float* __restrict__ b_hh,
                const float* __restrict__ Wp,
                const float* __restrict__ bp,
                float4* __restrict__ mats,      // [BB][S][NQ]
                float* __restrict__ last_bv)
{
  const int b    = blockIdx.x;
  const int tid  = threadIdx.x;
  const int lane = tid & 63;
  const int w    = tid >> 6;

  __shared__ __align__(16) float xh[36];      // x only: snap(9) + amps(27)
  __shared__ float gbuf[512];
  __shared__ float prj[27];

  // ---- weights into registers (reused all 15 steps)
  float4 wih[9], whh[32];
  {
    const float4* wi = (const float4*)(W_ih + tid*36);
    #pragma unroll
    for (int k = 0; k < 9; ++k) wih[k] = wi[k];
    const float4* wh = (const float4*)(W_hh + tid*H);
    #pragma unroll
    for (int k = 0; k < 32; ++k) whh[k] = wh[k];
  }
  const float bias = b_ih[tid] + b_hh[tid];
  float2 wpv[4]; float bpv[4];
  #pragma unroll
  for (int i = 0; i < 4; ++i) {
    int u = w + 8*i;
    if (u < 27) { wpv[i] = *(const float2*)(Wp + u*H + 2*lane); bpv[i] = bp[u]; }
    else        { wpv[i] = make_float2(0.f, 0.f); bpv[i] = 0.f; }
  }

  // ---- c and h register-resident on EVERY wave (redundant copies, 2/lane)
  float cc0 = c0[b*H + 2*lane], cc1 = c0[b*H + 2*lane + 1];
  float h0v = h0[b*H + 2*lane], h1v = h0[b*H + 2*lane + 1];

  // ---- pristine psi0 in wave-0 registers: flat = j*64 + lane
  float pr0[8], pi0[8], norm0 = 0.f;
  if (w == 0) {
    #pragma unroll
    for (int j = 0; j < 8; ++j) {
      pr0[j] = rho[b*1024 + j*64 + lane];
      pi0[j] = rho[b*1024 + 512 + j*64 + lane];
    }
    float ls = 0.f;
    #pragma unroll
    for (int j = 0; j < 8; ++j) ls += pr0[j]*pr0[j] + pi0[j]*pi0[j];
    norm0 = wave_red_sum(ls);
  }

  // ---- init x in LDS; t=0 mats straight from global inputs
  if (tid < NQ)  xh[tid]      = snapshot[b*NQ + tid];
  if (tid < 27)  xh[NQ + tid] = bcv[b*27 + tid];
  if (tid < NQ) {
    float s  = snapshot[b*NQ + tid];
    float v0 = bcv[b*27 + tid*3];
    float v1 = bcv[b*27 + tid*3 + 1];
    float v2 = bcv[b*27 + tid*3 + 2];
    mats[(b*S + 0)*NQ + tid] = make_float4(
        0.5f*(1.f + 3.f*s*v2), 1.5f*s*v0, -1.5f*s*v1, 0.5f*(1.f - 3.f*s*v2));
  }

  // ---- pre-loop ghh from h0 registers (readlane broadcast, no LDS)
  float ghh = bias;
  #pragma unroll
  for (int j = 0; j < 32; ++j) {
    float4 wv = whh[j];
    ghh += wv.x*RL(h0v, 2*j)     + wv.y*RL(h1v, 2*j)
         + wv.z*RL(h0v, 2*j + 1) + wv.w*RL(h1v, 2*j + 1);
  }
  __syncthreads();                                        // B0: xh ready

  for (int t = 1; t < S; ++t) {
    // ---- X: finish gates = ghh + W_ih * x   (9 LDS b128 reads)
    {
      const float4* x4 = (const float4*)xh;
      float g0 = ghh, g1 = 0.f, g2 = 0.f, g3 = 0.f;
      #pragma unroll
      for (int k = 0; k < 9; ++k) {
        float4 wv = wih[k], xv = x4[k];
        g0 += wv.x*xv.x; g1 += wv.y*xv.y; g2 += wv.z*xv.z; g3 += wv.w*xv.w;
      }
      gbuf[tid] = (g0 + g1) + (g2 + g3);
    }
    __syncthreads();                                      // B1: gbuf ready

    // ---- C: cell update, every wave redundantly (h in registers)
    {
      float2 gI = *(const float2*)(gbuf + 2*lane);
      float2 gF = *(const float2*)(gbuf + 128 + 2*lane);
      float2 gG = *(const float2*)(gbuf + 256 + 2*lane);
      float2 gO = *(const float2*)(gbuf + 384 + 2*lane);
      cc0 = sigf(gF.x)*cc0 + sigf(gI.x)*tanhfast(gG.x);
      cc1 = sigf(gF.y)*cc1 + sigf(gI.y)*tanhfast(gG.y);
      h0v = sigf(gO.x)*tanhfast(cc0);
      h1v = sigf(gO.y)*tanhfast(cc1);
    }
    // ---- projection logits: unit u = w + 8i, DPP wave reduction (reg h)
    #pragma unroll
    for (int i = 0; i < 4; ++i) {
      float p = wave_red_sum(wpv[i].x*h0v + wpv[i].y*h1v);
      int u = w + 8*i;
      if (u < 27 && lane == 0) prj[u] = p + bpv[i];
    }
    __syncthreads();                                      // B2: prj ready

    // ---- wave 0: softmax -> amps; deferred-norm collapse; emit
    //      (waves 1-7 skip straight to the ghh below -> overlap)
    if (w == 0) {
      float a1 = 0.f, a2 = 0.f, a3 = 0.f;
      float k0v = 0.f, k1rv = 0.f, k1iv = 0.f;
      if (lane < NQ) {
        float l0 = prj[lane*3], l1 = prj[lane*3+1], l2 = prj[lane*3+2];
        float mx = fmaxf(l0, fmaxf(l1, l2));
        float e0 = __expf(l0 - mx), e1 = __expf(l1 - mx), e2 = __expf(l2 - mx);
        float inv = RCP(e0 + e1 + e2);
        a1 = sqrtf(e0*inv); a2 = sqrtf(e1*inv); a3 = sqrtf(e2*inv);
        float an = sqrtf(a1*a1 + a2*a2 + a3*a3);
        float t3 = a3 + an;
        float n1 = RSQ(2.f*an*t3);
        k0v = n1*t3; k1rv = n1*a1; k1iv = -n1*a2;  // conj(p+) coefficients
      }
      float part[9];

      // q0: register bit 2 (no cross-lane)
      float r4[4], i4[4];
      {
        const float K0 = RL(k0v,0), K1r = RL(k1rv,0), K1i = RL(k1iv,0);
        float lp = 0.f;
        #pragma unroll
        for (int j = 0; j < 4; ++j) {
          r4[j] = K0*pr0[j] + K1r*pr0[j+4] - K1i*pi0[j+4];
          i4[j] = K0*pi0[j] + K1r*pi0[j+4] + K1i*pr0[j+4];
          lp += r4[j]*r4[j] + i4[j]*i4[j];
        }
        part[0] = lp;
      }
      // q1: register bit 1
      float r2[2], i2[2];
      {
        const float K0 = RL(k0v,1), K1r = RL(k1rv,1), K1i = RL(k1iv,1);
        float lp = 0.f;
        #pragma unroll
        for (int j = 0; j < 2; ++j) {
          r2[j] = K0*r4[j] + K1r*r4[j+2] - K1i*i4[j+2];
          i2[j] = K0*i4[j] + K1r*i4[j+2] + K1i*r4[j+2];
          lp += r2[j]*r2[j] + i2[j]*i2[j];
        }
        part[1] = lp;
      }
      // q2: register bit 0
      float wr, wi_;
      {
        const float K0 = RL(k0v,2), K1r = RL(k1rv,2), K1i = RL(k1iv,2);
        wr  = K0*r2[0] + K1r*r2[1] - K1i*i2[1];
        wi_ = K0*i2[0] + K1r*i2[1] + K1i*r2[1];
        part[2] = wr*wr + wi_*wi_;
      }
      // q3, q4: partner lane+half via bpermute (half = 32, 16)
      #pragma unroll
      for (int q = 3; q < 5; ++q) {
        const int half = 32 >> (q - 3);
        const float K0 = RL(k0v,q), K1r = RL(k1rv,q), K1i = RL(k1iv,q);
        float pr = __shfl(wr,  lane + half, 64);
        float pi = __shfl(wi_, lane + half, 64);
        float nr = K0*wr  + K1r*pr - K1i*pi;
        float ni = K0*wi_ + K1r*pi + K1i*pr;
        wr = nr; wi_ = ni;
        part[q] = (lane < half) ? (nr*nr + ni*ni) : 0.f;
      }
      // q5..q8: partner lane+half via row_ror:(16-half)  [source = i+half]
      #pragma unroll
      for (int q = 5; q < NQ; ++q) {
        const int half = 32 >> (q - 3);
        const float K0 = RL(k0v,q), K1r = RL(k1rv,q), K1i = RL(k1iv,q);
        float pr, pi;
        if      (q == 5) { pr = DPP_ROR(wr, 8);  pi = DPP_ROR(wi_, 8);  }
        else if (q == 6) { pr = DPP_ROR(wr, 12); pi = DPP_ROR(wi_, 12); }
        else if (q == 7) { pr = DPP_ROR(wr, 14); pi = DPP_ROR(wi_, 14); }
        else             { pr = DPP_ROR(wr, 15); pi = DPP_ROR(wi_, 15); }
        float nr = K0*wr  + K1r*pr - K1i*pi;
        float ni = K0*wi_ + K1r*pi + K1i*pr;
        wr = nr; wi_ = ni;
        part[q] = (lane < half) ? (nr*nr + ni*ni) : 0.f;
      }
      // batched norm reductions (independent DPP chains)
      float L[9];
      #pragma unroll
      for (int q = 0; q < NQ; ++q) L[q] = wave_red_sum(part[q]);
      // s values: independent rcp per qubit (parallel, not a divide chain)
      float sv = 2.f*L[0] - norm0;
      #pragma unroll
      for (int q = 1; q < NQ; ++q) {
        float r = 2.f*L[q]*RCP(L[q-1]) - 1.f;
        sv = (lane == q) ? r : sv;
      }
      // emit: new x = [snap, amps] and mats row for this t
      if (lane < NQ) {
        xh[lane] = sv;
        xh[9 + lane*3]     = a1;
        xh[9 + lane*3 + 1] = a2;
        xh[9 + lane*3 + 2] = a3;
        mats[(b*S + t)*NQ + lane] = make_float4(
            0.5f*(1.f + 3.f*sv*a3), 1.5f*sv*a1,
            -1.5f*sv*a2,            0.5f*(1.f - 3.f*sv*a3));
      }
    }

    // ---- ghh for next step from register h (waves 1-7 run this during
    //      wave 0's collapse; wave 0 appends it after)
    if (t < S - 1) {
      float g = bias;
      #pragma unroll
      for (int j = 0; j < 32; ++j) {
        float4 wv = whh[j];
        g += wv.x*RL(h0v, 2*j)     + wv.y*RL(h1v, 2*j)
           + wv.z*RL(h0v, 2*j + 1) + wv.w*RL(h1v, 2*j + 1);
      }
      ghh = g;
    }
    __syncthreads();                                      // B3: xh ready
  }

  if (tid < 27) last_bv[b*27 + tid] = xh[9 + tid];
}

// ---------------------------------------------------------------------------
// Kernel 2: out[b] = (1/S) sum_t Top(q0..3,16x16) (x) Bot(q4..8,32x32).
// v5: 2 rT x 4 rB rows per block, grid (64,16) = 1024 blocks.
// Staging writes are ENTRY-STRIDED (thread e writes entries e+512i) so
// consecutive lanes hit consecutive float2 -> 2-way bank aliasing (free).
// b128 bot reads (8 distinct addrs/wave = broadcast), nontemporal stores.
// ---------------------------------------------------------------------------
__device__ __forceinline__ void herm_entry(float4 m, int rb, int cb, float& er, float& ei) {
  if (rb == 0) { if (cb == 0) { er = m.x; ei = 0.f; } else { er = m.y; ei = m.z; } }
  else         { if (cb == 0) { er = m.y; ei = -m.z; } else { er = m.w; ei = 0.f; } }
}

__device__ __forceinline__ void nt_store4(float* p, float x, float y, float z, float w) {
  vfloat4 v; v.x = x; v.y = y; v.z = z; v.w = w;
  __builtin_nontemporal_store(v, (vfloat4*)p);
}

__global__ __launch_bounds__(512, 2)
void kron_kernel(const float4* __restrict__ mats_g, float* __restrict__ out)
{
  const int b   = blockIdx.y;
  const int bm  = blockIdx.x;          // rTp = bm>>3 (rT pair), rg = bm&7 (rB grp)
  const int tid = threadIdx.x;
  const int rTp = bm >> 3;
  const int rg  = bm & 7;

  __shared__ float4 matsh[S*NQ];                  // 2.3 KB
  __shared__ float2 top[S][2][16];                // 4 KB  [t][rTi][cT]
  __shared__ __align__(16) float2 bot[4][S][32];  // 16 KB [r][t][cB]

  if (tid < S*NQ) matsh[tid] = mats_g[b*S*NQ + tid];
  __syncthreads();

  {                                    // top: 512 entries, one per thread
    int t = tid >> 5, rTi = (tid >> 4) & 1, cT = tid & 15;
    int rT = rTp*2 + rTi;
    float re = 1.f, im = 0.f;
    #pragma unroll
    for (int q = 0; q < 4; ++q) {
      int rb = (rT >> (3 - q)) & 1, cb = (cT >> (3 - q)) & 1;
      float er, ei; herm_entry(matsh[t*NQ + q], rb, cb, er, ei);
      float nr = re*er - im*ei; im = re*ei + im*er; re = nr;
    }
    top[t][rTi][cT] = make_float2(re, im);
  }
  // bot: 2048 entries, entry-strided (conflict-free writes)
  #pragma unroll
  for (int i = 0; i < 4; ++i) {
    int n  = tid + 512*i;
    int r_ = n >> 9, t_ = (n >> 5) & 15, cB = n & 31;
    int rB = rg*4 + r_;
    float re = 1.f, im = 0.f;
    #pragma unroll
    for (int q = 0; q < 5; ++q) {
      int rb = (rB >> (4 - q)) & 1, cb = (cB >> (4 - q)) & 1;
      float er, ei; herm_entry(matsh[t_*NQ + 4 + q], rb, cb, er, ei);
      float nr = re*er - im*ei; im = re*ei + im*er; re = nr;
    }
    bot[r_][t_][cB] = make_float2(re, im);
  }
  __syncthreads();

  const int rb = tid >> 7;             // rB index within block (0..3)
  const int c0 = (tid & 127) << 2;     // 4 consecutive cols
  const int cT = c0 >> 5, cB = c0 & 31;
  float4 a0r = make_float4(0,0,0,0), a0i = make_float4(0,0,0,0);
  float4 a1r = make_float4(0,0,0,0), a1i = make_float4(0,0,0,0);
  #pragma unroll
  for (int t = 0; t < S; ++t) {
    float4 b01 = *(const float4*)&bot[rb][t][cB];      // cols cB, cB+1
    float4 b23 = *(const float4*)&bot[rb][t][cB + 2];  // cols cB+2, cB+3
    float2 tA = top[t][0][cT];
    float2 tB = top[t][1][cT];
    a0r.x += tA.x*b01.x - tA.y*b01.y;  a0i.x += tA.x*b01.y + tA.y*b01.x;
    a0r.y += tA.x*b01.z - tA.y*b01.w;  a0i.y += tA.x*b01.w + tA.y*b01.z;
    a0r.z += tA.x*b23.x - tA.y*b23.y;  a0i.z += tA.x*b23.y + tA.y*b23.x;
    a0r.w += tA.x*b23.z - tA.y*b23.w;  a0i.w += tA.x*b23.w + tA.y*b23.z;
    a1r.x += tB.x*b01.x - tB.y*b01.y;  a1i.x += tB.x*b01.y + tB.y*b01.x;
    a1r.y += tB.x*b01.z - tB.y*b01.w;  a1i.y += tB.x*b01.w + tB.y*b01.z;
    a1r.z += tB.x*b23.x - tB.y*b23.y;  a1i.z += tB.x*b23.y + tB.y*b23.x;
    a1r.w += tB.x*b23.z - tB.y*b23.w;  a1i.w += tB.x*b23.w + tB.y*b23.z;
  }
  const float invS = 1.f/16.f;
  const int rowA = (rTp*2)*32 + rg*4 + rb;   // rT = 2*rTp
  const int rowB = rowA + 32;                // rT = 2*rTp + 1
  size_t baseA = ((size_t)b*2)*DD + (size_t)rowA*D + c0;
  size_t baseB = ((size_t)b*2)*DD + (size_t)rowB*D + c0;
  nt_store4(out + baseA,      a0r.x*invS, a0r.y*invS, a0r.z*invS, a0r.w*invS);
  nt_store4(out + baseA + DD, a0i.x*invS, a0i.y*invS, a0i.z*invS, a0i.w*invS);
  nt_store4(out + baseB,      a1r.x*invS, a1r.y*invS, a1r.z*invS, a1r.w*invS);
  nt_store4(out + baseB + DD, a1i.x*invS, a1i.y*invS, a1i.z*invS, a1i.w*invS);
}

extern "C" void kernel_launch(void* const* d_in, const int* in_sizes, int n_in,
                              void* d_out, int out_size, void* d_ws, size_t ws_size,
                              hipStream_t stream) {
  const float* snapshot = (const float*)d_in[0];
  const float* bcv      = (const float*)d_in[1];
  const float* rho      = (const float*)d_in[2];
  const float* h0       = (const float*)d_in[3];
  const float* c0       = (const float*)d_in[4];
  const float* W_ih     = (const float*)d_in[5];
  const float* W_hh     = (const float*)d_in[6];
  const float* b_ih     = (const float*)d_in[7];
  const float* b_hh     = (const float*)d_in[8];
  const float* Wp       = (const float*)d_in[9];
  const float* bp       = (const float*)d_in[10];

  float*  out     = (float*)d_out;
  float4* mats    = (float4*)d_ws;                 // 16*16*9 float4 = 36 KB
  float*  last_bv = out + (size_t)BB*2*DD;         // output chunk 1

  seq_kernel<<<BB, 512, 0, stream>>>(snapshot, bcv, rho, h0, c0,
                                     W_ih, W_hh, b_ih, b_hh, Wp, bp,
                                     mats, last_bv);

  dim3 grid(64, BB);
  kron_kernel<<<grid, 512, 0, stream>>>(mats, out);
}